// Round 6
// baseline (275.690 us; speedup 1.0000x reference)
//
#include <hip/hip_runtime.h>
#include <hip/hip_bf16.h>

typedef unsigned short u16;
typedef unsigned int u32;
typedef __attribute__((ext_vector_type(8))) __bf16 bf16x8;
typedef __attribute__((ext_vector_type(4))) float f32x4;
typedef __attribute__((ext_vector_type(16))) float f32x16;

constexpr int Bz = 2, Sq = 2048, Dm = 1024, Hn = 16, DK = 64;

__device__ __forceinline__ u16 f2bf(float f) {
    u32 u = __builtin_bit_cast(u32, f);
    return (u16)((u + 0x7FFFu + ((u >> 16) & 1u)) >> 16);   // RNE
}

__device__ __forceinline__ u32 pack_bf16(float a, float b) {
#if __has_builtin(__builtin_amdgcn_cvt_pk_bf16_f32)
    return __builtin_bit_cast(u32, __builtin_amdgcn_cvt_pk_bf16_f32(a, b));
#else
    return (u32)f2bf(a) | ((u32)f2bf(b) << 16);
#endif
}

__device__ __forceinline__ bf16x8 lds_frag(const u16* p) {
    return __builtin_bit_cast(bf16x8, *(const uint4*)p);
}
__device__ __forceinline__ bf16x8 gfrag(const u16* p) {
    return __builtin_bit_cast(bf16x8, *(const uint4*)p);
}
__device__ __forceinline__ int swz(int r) { return (r ^ (r >> 3)) & 7; }

// async global->LDS, 16B per lane; dest = wave-uniform base + lane*16
__device__ __forceinline__ void gll16(const u16* g, u16* l) {
    __builtin_amdgcn_global_load_lds(
        (const __attribute__((address_space(1))) void*)g,
        (__attribute__((address_space(3))) void*)l, 16, 0, 0);
}

// ---------------------------------------------------------------------------
// Kernel 1 (fused prep): z<3: cast q/k/v fp32->bf16. z==3:
//   bx<1024     : transpose+cast the 4 weights (64x64 tiles) -> Wt [N,K] bf16
//   bx==1024/5  : per-batch key compaction scan: comp[s] = compacted position
//                 (active keys mask==0 -> front ranks; masked keys parked at
//                 tail), bias (compacted) 0 / -1e10*log2e, nk[b] = #active.
// ---------------------------------------------------------------------------
__global__ __launch_bounds__(256) void mha_prep(
    const float* __restrict__ q, const float* __restrict__ k,
    const float* __restrict__ v,
    const float* __restrict__ w0, const float* __restrict__ w1,
    const float* __restrict__ w2, const float* __restrict__ w3,
    const int* __restrict__ mask,
    u16* __restrict__ qkv_dst, u16* __restrict__ wt_dst,
    float* __restrict__ biasg, int* __restrict__ compg, int* __restrict__ nkg)
{
    __shared__ float tl[64 * 65];
    __shared__ int sc[256];
    const int z = blockIdx.z, tid = threadIdx.x;
    if (z < 3) {
        const float* s = (z == 0) ? q : (z == 1) ? k : v;
        u16* d = qkv_dst + (size_t)z * 4 * 1024 * 1024;
        size_t i = ((size_t)blockIdx.x * 256 + tid) * 8;
        float4 a = *(const float4*)(s + i);
        float4 b = *(const float4*)(s + i + 4);
        *(uint4*)(d + i) = make_uint4(pack_bf16(a.x, a.y), pack_bf16(a.z, a.w),
                                      pack_bf16(b.x, b.y), pack_bf16(b.z, b.w));
        return;
    }
    const int bx = blockIdx.x;
    if (bx >= 1026) return;
    if (bx >= 1024) {   // compaction scan for batch b
        const int b = bx - 1024;
        const int* mp = mask + b * Sq;
        int4 m0_ = ((const int4*)mp)[tid * 2];
        int4 m1_ = ((const int4*)mp)[tid * 2 + 1];
        int a[8];
        a[0] = (m0_.x == 0); a[1] = (m0_.y == 0); a[2] = (m0_.z == 0); a[3] = (m0_.w == 0);
        a[4] = (m1_.x == 0); a[5] = (m1_.y == 0); a[6] = (m1_.z == 0); a[7] = (m1_.w == 0);
        int cnt = 0;
#pragma unroll
        for (int j = 0; j < 8; j++) cnt += a[j];
        sc[tid] = cnt;
        __syncthreads();
        for (int off = 1; off < 256; off <<= 1) {
            int u = (tid >= off) ? sc[tid - off] : 0;
            int vv = sc[tid];
            __syncthreads();
            sc[tid] = vv + u;
            __syncthreads();
        }
        const int incl = sc[tid];
        const int nk = sc[255];
        int pa = incl - cnt;            // actives before my 8 elems
        int pi = nk + tid * 8 - pa;     // nk + inactives before
        int* cp = compg + b * Sq;
        float* bbp = biasg + b * Sq;
#pragma unroll
        for (int j = 0; j < 8; j++) {
            int pos = a[j] ? pa++ : pi++;
            cp[tid * 8 + j] = pos;
            bbp[pos] = a[j] ? 0.f : -1.44269504e10f;
        }
        if (tid == 0) nkg[b] = nk;
        return;
    }
    // weight transpose: matrix zi, 64x64 tile (tr,tc)
    const int zi = bx >> 8, t = bx & 255, tr = t >> 4, tc = t & 15;
    const float* src = (zi == 0) ? w0 : (zi == 1) ? w1 : (zi == 2) ? w2 : w3;
    u16* d = wt_dst + (size_t)zi * Dm * Dm;
    {
        int r = tid >> 2, cq = (tid & 3) * 16;
        const float* sp = src + (size_t)(tr * 64 + r) * Dm + tc * 64 + cq;
#pragma unroll
        for (int j = 0; j < 4; j++) {
            float4 vv = *(const float4*)(sp + j * 4);
            tl[r * 65 + cq + j * 4 + 0] = vv.x;
            tl[r * 65 + cq + j * 4 + 1] = vv.y;
            tl[r * 65 + cq + j * 4 + 2] = vv.z;
            tl[r * 65 + cq + j * 4 + 3] = vv.w;
        }
    }
    __syncthreads();
    {
        int rr = tid >> 2, cc = (tid & 3) * 16;
        u16* dp = d + (size_t)(tc * 64 + rr) * Dm + tr * 64 + cc;
        u32 px[8];
#pragma unroll
        for (int j = 0; j < 8; j++)
            px[j] = pack_bf16(tl[(cc + 2 * j) * 65 + rr], tl[(cc + 2 * j + 1) * 65 + rr]);
        *(uint4*)dp       = make_uint4(px[0], px[1], px[2], px[3]);
        *(uint4*)(dp + 8) = make_uint4(px[4], px[5], px[6], px[7]);
    }
}

// ---------------------------------------------------------------------------
// GEMM core A (m97 structure): C[128 x 128] = A[128xK] @ B[128 x K]^T,
// K=1024, BK=64. 256 thr = 4 waves (2m x 2n), wave tile 64x64, acc[4][4].
// LDS 32 KB. global_load_lds staging, XOR-swizzled tiles.
// ---------------------------------------------------------------------------
__device__ __forceinline__ void gemm_core_128128(
    const u16* __restrict__ Ab, const u16* __restrict__ Bb,
    u16* As, u16* Bs, f32x4 (&acc)[4][4])
{
    const int tid = threadIdx.x, lane = tid & 63;
    const int wm = (tid >> 7) & 1, wn = (tid >> 6) & 1;
    const int frow = lane & 15, quad = lane >> 4;

#pragma unroll
    for (int mi = 0; mi < 4; mi++)
#pragma unroll
        for (int ni = 0; ni < 4; ni++) acc[mi][ni] = (f32x4){0.f, 0.f, 0.f, 0.f};

    for (int k0 = 0; k0 < 1024; k0 += 64) {
#pragma unroll
        for (int i = 0; i < 4; i++) {
            int id = tid + i * 256, r = id >> 3, c = id & 7;
            gll16(Ab + (size_t)r * 1024 + k0 + (c ^ swz(r)) * 8, As + (size_t)id * 8);
        }
#pragma unroll
        for (int i = 0; i < 4; i++) {
            int id = tid + i * 256, r = id >> 3, c = id & 7;
            gll16(Bb + (size_t)r * 1024 + k0 + (c ^ swz(r)) * 8, Bs + (size_t)id * 8);
        }
        __syncthreads();
#pragma unroll
        for (int ks = 0; ks < 2; ks++) {
            bf16x8 af[4], bfr[4];
#pragma unroll
            for (int mi = 0; mi < 4; mi++) {
                int r = wm * 64 + mi * 16 + frow;
                af[mi] = lds_frag(As + r * 64 + ((ks * 4 + quad) ^ swz(r)) * 8);
            }
#pragma unroll
            for (int ni = 0; ni < 4; ni++) {
                int r = wn * 64 + ni * 16 + frow;
                bfr[ni] = lds_frag(Bs + r * 64 + ((ks * 4 + quad) ^ swz(r)) * 8);
            }
#pragma unroll
            for (int mi = 0; mi < 4; mi++)
#pragma unroll
                for (int ni = 0; ni < 4; ni++)
                    acc[mi][ni] = __builtin_amdgcn_mfma_f32_16x16x32_bf16(
                        af[mi], bfr[ni], acc[mi][ni], 0, 0, 0);
        }
        __syncthreads();
    }
}

// ---------------------------------------------------------------------------
// GEMM core B (small tile, for oproj where N=1024 would give 1 block/CU
// with the 128x128 tile): C[128 x 64] = A[128xK] @ B[64 x K]^T.
// ---------------------------------------------------------------------------
__device__ __forceinline__ void gemm_core_12864(
    const u16* __restrict__ Ab, const u16* __restrict__ Bb,
    u16* As, u16* Bs, f32x4 (&acc)[4][2])
{
    const int tid = threadIdx.x, lane = tid & 63;
    const int wm = (tid >> 7) & 1, wn = (tid >> 6) & 1;
    const int frow = lane & 15, quad = lane >> 4;

#pragma unroll
    for (int mi = 0; mi < 4; mi++)
#pragma unroll
        for (int ni = 0; ni < 2; ni++) acc[mi][ni] = (f32x4){0.f, 0.f, 0.f, 0.f};

    for (int k0 = 0; k0 < 1024; k0 += 64) {
#pragma unroll
        for (int i = 0; i < 4; i++) {
            int id = tid + i * 256, r = id >> 3, c = id & 7;
            gll16(Ab + (size_t)r * 1024 + k0 + (c ^ swz(r)) * 8, As + (size_t)id * 8);
        }
#pragma unroll
        for (int i = 0; i < 2; i++) {
            int id = tid + i * 256, r = id >> 3, c = id & 7;
            gll16(Bb + (size_t)r * 1024 + k0 + (c ^ swz(r)) * 8, Bs + (size_t)id * 8);
        }
        __syncthreads();
#pragma unroll
        for (int ks = 0; ks < 2; ks++) {
            bf16x8 af[4], bfr[2];
#pragma unroll
            for (int mi = 0; mi < 4; mi++) {
                int r = wm * 64 + mi * 16 + frow;
                af[mi] = lds_frag(As + r * 64 + ((ks * 4 + quad) ^ swz(r)) * 8);
            }
#pragma unroll
            for (int ni = 0; ni < 2; ni++) {
                int r = wn * 32 + ni * 16 + frow;
                bfr[ni] = lds_frag(Bs + r * 64 + ((ks * 4 + quad) ^ swz(r)) * 8);
            }
#pragma unroll
            for (int mi = 0; mi < 4; mi++)
#pragma unroll
                for (int ni = 0; ni < 2; ni++)
                    acc[mi][ni] = __builtin_amdgcn_mfma_f32_16x16x32_bf16(
                        af[mi], bfr[ni], acc[mi][ni], 0, 0, 0);
        }
        __syncthreads();
    }
}

// ---------------------------------------------------------------------------
// Kernel 2: QKV projections, 128x128 tiles, 256 blocks per z (3/CU total).
// z=0: Q->[B,H,S,DK]; z=1: K->[B,H,comp(s),DK] (COMPACTED rows);
// z=2: swapped operands -> V'^T [B,H,DK,sp(comp(s))] (compacted, keys
// bit2/3-swapped so PV B-operand is register-natural).
// ---------------------------------------------------------------------------
__global__ __launch_bounds__(256, 3) void mha_proj_qkv(
    const u16* __restrict__ Qb, const u16* __restrict__ Kb, const u16* __restrict__ Vb,
    const u16* __restrict__ Wqt, const u16* __restrict__ Wkt, const u16* __restrict__ Wvt,
    const float* __restrict__ bq, const float* __restrict__ bk, const float* __restrict__ bv,
    const int* __restrict__ comp,
    u16* __restrict__ Qh, u16* __restrict__ Kh, u16* __restrict__ Vt)
{
    __shared__ __align__(16) u16 As[128 * 64];
    __shared__ __align__(16) u16 Bs[128 * 64];
    const int z = blockIdx.z, bx = blockIdx.x;
    const u16* Ab; const u16* Bb; const float* bias;
    int m0, n0;
    if (z < 2) {
        m0 = (bx & 31) * 128;        // 32 m-tiles minor: XCD = m_t%8, tokens clustered
        n0 = (bx >> 5) * 128;        // 8 n-tiles
        Ab = ((z == 0) ? Qb : Kb) + (size_t)m0 * Dm;
        Bb = ((z == 0) ? Wqt : Wkt) + (size_t)n0 * Dm;
        bias = (z == 0) ? bq : bk;
    } else {
        m0 = (bx >> 5) * 128;        // 8 m-tiles (outdim)
        n0 = (bx & 31) * 128;        // 32 n-tiles minor: XCD = n_t%8, Vb tokens clustered
        Ab = Wvt + (size_t)m0 * Dm;
        Bb = Vb + (size_t)n0 * Dm;
        bias = bv;
    }

    f32x4 acc[4][4];
    gemm_core_128128(Ab, Bb, As, Bs, acc);

    const int tid = threadIdx.x, lane = tid & 63;
    const int wm = (tid >> 7) & 1, wn = (tid >> 6) & 1;
    const int frow = lane & 15, quad = lane >> 4;
    u16* dstq = (z == 0) ? Qh : Kh;
#pragma unroll
    for (int mi = 0; mi < 4; mi++)
#pragma unroll
        for (int ni = 0; ni < 4; ni++)
#pragma unroll
            for (int r = 0; r < 4; r++) {
                int i = m0 + wm * 64 + mi * 16 + quad * 4 + r;
                int j = n0 + wn * 64 + ni * 16 + frow;
                if (z < 2) {
                    float val = acc[mi][ni][r] + bias[j];
                    int b = i >> 11, s = i & (Sq - 1);
                    int h = j >> 6, dk = j & (DK - 1);
                    int srow = (z == 1) ? comp[b * Sq + s] : s;
                    dstq[((size_t)(b * Hn + h) * Sq + srow) * DK + dk] = f2bf(val);
                } else {
                    float val = acc[mi][ni][r] + bias[i];
                    int h = i >> 6, dk = i & (DK - 1);
                    int bj = j >> 11, s = j & (Sq - 1);
                    int cs = comp[bj * Sq + s];
                    int sp = (cs & ~12) | ((cs & 4) << 1) | ((cs & 8) >> 1);  // swap bits 2,3
                    Vt[((size_t)(bj * Hn + h) * DK + dk) * Sq + sp] = f2bf(val);
                }
            }
}

// ---------------------------------------------------------------------------
// Kernel 3: flash attention over COMPACTED keys. R0-verified structure:
// 512 thr = 8 waves = 2 q-groups (wq: 32q -> 64 q/block) x 4 key-parities
// (p: 64 keys each of a 256-key staged tile, two 32-key register passes
// s=0,1). Runtime tile count nt = ceil(nk/256): compaction halves tiles.
// 256-key tiles amortize the per-tile fixed cost (drain barrier + staging
// issue) that dominated at 128-key tiles (R4), with NO extra per-wave
// register state (R0 measured 64 VGPR, zero spill at this exact mapping;
// R5's 4-q-group variant spilled: WRITE_SIZE 8192->34816 KB). Single
// buffer, LDS 65 KB -> 2 blocks/CU. No-max exp2 softmax, P register-
// resident, setprio(1) around MFMA, 2-barrier tree combine (R2-verified).
// __launch_bounds__(512,4): cap 128 regs. DO NOT raise the min-waves arg
// ((512,8) forced 64-cap -> catastrophic spill, R3).
// ---------------------------------------------------------------------------
__global__ __launch_bounds__(512, 4) void mha_attn(
    const u16* __restrict__ Qh, const u16* __restrict__ Kh, const u16* __restrict__ Vt,
    const float* __restrict__ biasg, const int* __restrict__ nkg,
    u16* __restrict__ X)
{
    const int bh = blockIdx.x;                 // b*16+h -> XCD = bh%8
    const int b = bh >> 4;
    const int q0 = blockIdx.y * 64;
    const int tid = threadIdx.x, lane = tid & 63, w = tid >> 6;
    const int wq = w & 1, p = w >> 1;          // q-group, key-parity 0..3
    const int qc = lane & 31, half = lane >> 5;
    constexpr float C2 = 0.125f * 1.44269504f; // 1/sqrt(DK) * log2(e)

    __shared__ __align__(16) u16 Ks[256 * 64]; // 32 KB [key][dk]
    __shared__ __align__(16) u16 Vs[64 * 256]; // 32 KB [d][key-slot]
    __shared__ float lsl[256];

    const u16* Qp = Qh + (size_t)bh * Sq * DK;
    const u16* Kp = Kh + (size_t)bh * Sq * DK;
    const u16* Vp = Vt + (size_t)bh * DK * Sq;
    const float* bp = biasg + b * Sq;
    const int nk = nkg[b];
    const int nt = (nk + 255) >> 8;            // tiles of 256 compacted keys

    // Q B-frags direct from global (once): lane n=qc; k = kc*16 + half*8 + j
    bf16x8 qf[4];
    {
        const u16* qrow = Qp + (size_t)(q0 + wq * 32 + qc) * DK + half * 8;
#pragma unroll
        for (int kc = 0; kc < 4; kc++) qf[kc] = gfrag(qrow + kc * 16);
    }

    float l_l = 0.f;
    f32x16 o0, o1;
#pragma unroll
    for (int i = 0; i < 16; i++) { o0[i] = 0.f; o1[i] = 0.f; }

    for (int it = 0; it < nt; it++) {
        const int kb = it * 256;
        // ---- stage K [256][64] + V [64][256] (64 KB, 8 gll16/thread) ----
#pragma unroll
        for (int i = 0; i < 4; i++) {
            int id = tid + i * 512;                 // 0..2047
            int kr = id >> 3, kc_ = id & 7;
            gll16(Kp + (size_t)(kb + kr) * DK + (kc_ ^ swz(kr)) * 8, Ks + (size_t)id * 8);
            int vr = id >> 5, vc = id & 31;
            gll16(Vp + (size_t)vr * Sq + kb + ((vc ^ (vr & 31)) * 8), Vs + (size_t)id * 8);
        }
        __syncthreads();

#pragma unroll
        for (int s = 0; s < 2; s++) {
            // ---- S^T = K Q^T on this wave's 32-key sub-slice ----
            const int kr = p * 64 + s * 32 + qc;
            const int K0 = kb + p * 64 + s * 32;
            f32x16 sT;
#pragma unroll
            for (int i = 0; i < 16; i++) sT[i] = 0.f;
            __builtin_amdgcn_s_setprio(1);
#pragma unroll
            for (int kc = 0; kc < 4; kc++) {
                bf16x8 ka = lds_frag(Ks + kr * 64 + ((kc * 2 + half) ^ swz(kr)) * 8);
                sT = __builtin_amdgcn_mfma_f32_32x32x16_bf16(ka, qf[kc], sT, 0, 0, 0);
            }
            __builtin_amdgcn_s_setprio(0);

            // ---- no-max exp2 softmax; C row(key) = (r&3)+8*(r>>2)+4*half ----
            float t[16], rs = 0.f;
#pragma unroll
            for (int g = 0; g < 4; g++) {
                float4 mb = *(const float4*)(bp + K0 + 8 * g + 4 * half);
#pragma unroll
                for (int r = 0; r < 4; r++) {
                    float bb = (r == 0) ? mb.x : (r == 1) ? mb.y : (r == 2) ? mb.z : mb.w;
                    float a = __builtin_amdgcn_exp2f(fmaf(sT[g * 4 + r], C2, bb));
                    t[g * 4 + r] = a; rs += a;
                }
            }
            l_l += rs;

            // ---- pack P (register-resident; slot = key w/ bits2,3 swapped) ----
            u32 pk[8];
#pragma unroll
            for (int i = 0; i < 8; i++) pk[i] = pack_bf16(t[2 * i], t[2 * i + 1]);

            // ---- O^T += V P^T (2 MFMAs of k=16 per d-half) ----
            __builtin_amdgcn_s_setprio(1);
#pragma unroll
            for (int kc = 0; kc < 2; kc++) {
                bf16x8 pf = __builtin_bit_cast(bf16x8,
                    make_uint4(pk[4 * kc], pk[4 * kc + 1], pk[4 * kc + 2], pk[4 * kc + 3]));
                int ch = p * 8 + s * 4 + kc * 2 + half;
                bf16x8 va0 = lds_frag(Vs + qc * 256 + ((ch ^ (qc & 31)) * 8));
                bf16x8 va1 = lds_frag(Vs + (32 + qc) * 256 + ((ch ^ ((32 + qc) & 31)) * 8));
                o0 = __builtin_amdgcn_mfma_f32_32x32x16_bf16(va0, pf, o0, 0, 0, 0);
                o1 = __builtin_amdgcn_mfma_f32_32x32x16_bf16(va1, pf, o1, 0, 0, 0);
            }
            __builtin_amdgcn_s_setprio(0);
        }
        __syncthreads();
    }

    // ---- tree combine of 4 key-parity partials (2 barriers) ----
    l_l += __shfl_xor(l_l, 32);
    float* fcb = (float*)Ks;                 // 32 KB = 4 segs x 8 KB
    if (p >= 2) {                            // round 1 write: p=2->seg(wq,0), p=3->seg(wq,1)
        float* fc = fcb + (size_t)(wq * 2 + (p & 1)) * 2048;
#pragma unroll
        for (int r = 0; r < 16; r++) fc[r * 64 + lane] = o0[r];
#pragma unroll
        for (int r = 0; r < 16; r++) fc[(16 + r) * 64 + lane] = o1[r];
        lsl[(wq * 2 + (p & 1)) * 64 + lane] = l_l;
    }
    __syncthreads();
    if (p < 2) {                             // round 1 add (parallel on p=0,1)
        float* fc = fcb + (size_t)(wq * 2 + p) * 2048;
#pragma unroll
        for (int r = 0; r < 16; r++) o0[r] += fc[r * 64 + lane];
#pragma unroll
        for (int r = 0; r < 16; r++) o1[r] += fc[(16 + r) * 64 + lane];
        l_l += lsl[(wq * 2 + p) * 64 + lane];
    }
    if (p == 1) {                            // round 2 write (same seg it just read)
        float* fc = fcb + (size_t)(wq * 2 + 1) * 2048;
#pragma unroll
        for (int r = 0; r < 16; r++) fc[r * 64 + lane] = o0[r];
#pragma unroll
        for (int r = 0; r < 16; r++) fc[(16 + r) * 64 + lane] = o1[r];
        lsl[(wq * 2 + 1) * 64 + lane] = l_l;
    }
    __syncthreads();
    if (p == 0) {
        float* fc = fcb + (size_t)(wq * 2 + 1) * 2048;
#pragma unroll
        for (int r = 0; r < 16; r++) o0[r] += fc[r * 64 + lane];
#pragma unroll
        for (int r = 0; r < 16; r++) o1[r] += fc[(16 + r) * 64 + lane];
        l_l += lsl[(wq * 2 + 1) * 64 + lane];
        float inv = 1.0f / l_l;
        const int qg = q0 + wq * 32 + qc;
        u16* Xp = X + (size_t)(b * Sq + qg) * Dm + (bh & 15) * DK;
#pragma unroll
        for (int g = 0; g < 4; g++) {
            *(uint2*)&Xp[8 * g + 4 * half] =
                make_uint2(pack_bf16(o0[g * 4 + 0] * inv, o0[g * 4 + 1] * inv),
                           pack_bf16(o0[g * 4 + 2] * inv, o0[g * 4 + 3] * inv));
            *(uint2*)&Xp[32 + 8 * g + 4 * half] =
                make_uint2(pack_bf16(o1[g * 4 + 0] * inv, o1[g * 4 + 1] * inv),
                           pack_bf16(o1[g * 4 + 2] * inv, o1[g * 4 + 3] * inv));
        }
    }
}

// ---------------------------------------------------------------------------
// Kernel 4: out = X @ Wo + bo (fp32). 128x64 tiles, m-major -> 512 blocks
// (2 blocks/CU; the 128x128 tile would leave 1/CU here).
// ---------------------------------------------------------------------------
__global__ __launch_bounds__(256) void mha_oproj(
    const u16* __restrict__ X, const u16* __restrict__ Wot,
    const float* __restrict__ bo, float* __restrict__ out)
{
    __shared__ __align__(16) u16 As[128 * 64];
    __shared__ __align__(16) u16 Bs[64 * 64];
    const int bx = blockIdx.x;
    const int m0 = (bx & 31) * 128, n0 = (bx >> 5) * 64;
    f32x4 acc[4][2];
    gemm_core_12864(X + (size_t)m0 * Dm, Wot + (size_t)n0 * Dm, As, Bs, acc);
    const int tid = threadIdx.x, lane = tid & 63;
    const int wm = (tid >> 7) & 1, wn = (tid >> 6) & 1;
    const int frow = lane & 15, quad = lane >> 4;
#pragma unroll
    for (int mi = 0; mi < 4; mi++)
#pragma unroll
        for (int ni = 0; ni < 2; ni++)
#pragma unroll
            for (int r = 0; r < 4; r++) {
                int m = m0 + wm * 64 + mi * 16 + quad * 4 + r;
                int n = n0 + wn * 32 + ni * 16 + frow;
                out[(size_t)m * Dm + n] = acc[mi][ni][r] + bo[n];
            }
}

// ---------------------------------------------------------------------------
extern "C" void kernel_launch(void* const* d_in, const int* in_sizes, int n_in,
                              void* d_out, int out_size, void* d_ws, size_t ws_size,
                              hipStream_t stream)
{
    const float* qin  = (const float*)d_in[0];
    const float* kin  = (const float*)d_in[1];
    const float* vin  = (const float*)d_in[2];
    const int*   mask = (const int*)d_in[3];
    const float* Wq   = (const float*)d_in[4];
    const float* bq   = (const float*)d_in[5];
    const float* Wk   = (const float*)d_in[6];
    const float* bk   = (const float*)d_in[7];
    const float* Wv   = (const float*)d_in[8];
    const float* bv   = (const float*)d_in[9];
    const float* Wo   = (const float*)d_in[10];
    const float* bo   = (const float*)d_in[11];
    float* out = (float*)d_out;

    u16* ws = (u16*)d_ws;
    const size_t MW = (size_t)Dm * Dm;
    const size_t MT = (size_t)Bz * Sq * Dm;
    u16* Wqt = ws;
    u16* Wkt = ws + MW;
    u16* Wvt = ws + 2 * MW;
    u16* Wot = ws + 3 * MW;
    u16* Qb  = ws + 4 * MW;
    u16* Kb  = Qb + MT;
    u16* Vb  = Kb + MT;
    u16* Qh  = Vb + MT;
    u16* Kh  = Qh + MT;
    u16* Vt  = Kh + MT;
    float* biasg = (float*)(Vt + MT);          // 16 KB (compacted bias)
    int*   compg = (int*)(biasg + Bz * Sq);    // 16 KB (key -> compact pos)
    int*   nkg   = (int*)(compg + Bz * Sq);    // 2 ints (#active keys per b)
    u16* X   = Qb;                             // Qb dead after proj

    hipLaunchKernelGGL(mha_prep, dim3(2048, 1, 4), dim3(256), 0, stream,
                       qin, kin, vin, Wq, Wk, Wv, Wo, mask, Qb, Wqt, biasg, compg, nkg);
    hipLaunchKernelGGL(mha_proj_qkv, dim3(256, 1, 3), dim3(256), 0, stream,
                       Qb, Kb, Vb, Wqt, Wkt, Wvt, bq, bk, bv, compg, Qh, Kh, Vt);
    hipLaunchKernelGGL(mha_attn, dim3(32, 32), dim3(512), 0, stream,
                       Qh, Kh, Vt, biasg, nkg, X);
    hipLaunchKernelGGL(mha_oproj, dim3(512), dim3(256), 0, stream,
                       X, Wot, bo, out);
}

// Round 7
// 226.565 us; speedup vs baseline: 1.2168x; 1.2168x over previous
//
#include <hip/hip_runtime.h>
#include <hip/hip_bf16.h>

typedef unsigned short u16;
typedef unsigned int u32;
typedef __attribute__((ext_vector_type(8))) __bf16 bf16x8;
typedef __attribute__((ext_vector_type(4))) float f32x4;
typedef __attribute__((ext_vector_type(16))) float f32x16;

constexpr int Bz = 2, Sq = 2048, Dm = 1024, Hn = 16, DK = 64;

__device__ __forceinline__ u16 f2bf(float f) {
    u32 u = __builtin_bit_cast(u32, f);
    return (u16)((u + 0x7FFFu + ((u >> 16) & 1u)) >> 16);   // RNE
}

__device__ __forceinline__ u32 pack_bf16(float a, float b) {
#if __has_builtin(__builtin_amdgcn_cvt_pk_bf16_f32)
    return __builtin_bit_cast(u32, __builtin_amdgcn_cvt_pk_bf16_f32(a, b));
#else
    return (u32)f2bf(a) | ((u32)f2bf(b) << 16);
#endif
}

__device__ __forceinline__ bf16x8 lds_frag(const u16* p) {
    return __builtin_bit_cast(bf16x8, *(const uint4*)p);
}
__device__ __forceinline__ bf16x8 gfrag(const u16* p) {
    return __builtin_bit_cast(bf16x8, *(const uint4*)p);
}
__device__ __forceinline__ int swz(int r) { return (r ^ (r >> 3)) & 7; }

// async global->LDS, 16B per lane; dest = wave-uniform base + lane*16
__device__ __forceinline__ void gll16(const u16* g, u16* l) {
    __builtin_amdgcn_global_load_lds(
        (const __attribute__((address_space(1))) void*)g,
        (__attribute__((address_space(3))) void*)l, 16, 0, 0);
}

// ---------------------------------------------------------------------------
// Kernel 1 (fused prep): z<3: cast q/k/v fp32->bf16. z==3:
//   bx<1024     : transpose+cast the 4 weights (64x64 tiles) -> Wt [N,K] bf16
//   bx==1024/5  : per-batch key compaction scan: comp[s] = compacted position
//                 (active keys mask==0 -> front ranks; masked keys parked at
//                 tail), bias (compacted) 0 / -1e10*log2e, nk[b] = #active.
// ---------------------------------------------------------------------------
__global__ __launch_bounds__(256) void mha_prep(
    const float* __restrict__ q, const float* __restrict__ k,
    const float* __restrict__ v,
    const float* __restrict__ w0, const float* __restrict__ w1,
    const float* __restrict__ w2, const float* __restrict__ w3,
    const int* __restrict__ mask,
    u16* __restrict__ qkv_dst, u16* __restrict__ wt_dst,
    float* __restrict__ biasg, int* __restrict__ compg, int* __restrict__ nkg)
{
    __shared__ float tl[64 * 65];
    __shared__ int sc[256];
    const int z = blockIdx.z, tid = threadIdx.x;
    if (z < 3) {
        const float* s = (z == 0) ? q : (z == 1) ? k : v;
        u16* d = qkv_dst + (size_t)z * 4 * 1024 * 1024;
        size_t i = ((size_t)blockIdx.x * 256 + tid) * 8;
        float4 a = *(const float4*)(s + i);
        float4 b = *(const float4*)(s + i + 4);
        *(uint4*)(d + i) = make_uint4(pack_bf16(a.x, a.y), pack_bf16(a.z, a.w),
                                      pack_bf16(b.x, b.y), pack_bf16(b.z, b.w));
        return;
    }
    const int bx = blockIdx.x;
    if (bx >= 1026) return;
    if (bx >= 1024) {   // compaction scan for batch b
        const int b = bx - 1024;
        const int* mp = mask + b * Sq;
        int4 m0_ = ((const int4*)mp)[tid * 2];
        int4 m1_ = ((const int4*)mp)[tid * 2 + 1];
        int a[8];
        a[0] = (m0_.x == 0); a[1] = (m0_.y == 0); a[2] = (m0_.z == 0); a[3] = (m0_.w == 0);
        a[4] = (m1_.x == 0); a[5] = (m1_.y == 0); a[6] = (m1_.z == 0); a[7] = (m1_.w == 0);
        int cnt = 0;
#pragma unroll
        for (int j = 0; j < 8; j++) cnt += a[j];
        sc[tid] = cnt;
        __syncthreads();
        for (int off = 1; off < 256; off <<= 1) {
            int u = (tid >= off) ? sc[tid - off] : 0;
            int vv = sc[tid];
            __syncthreads();
            sc[tid] = vv + u;
            __syncthreads();
        }
        const int incl = sc[tid];
        const int nk = sc[255];
        int pa = incl - cnt;            // actives before my 8 elems
        int pi = nk + tid * 8 - pa;     // nk + inactives before
        int* cp = compg + b * Sq;
        float* bbp = biasg + b * Sq;
#pragma unroll
        for (int j = 0; j < 8; j++) {
            int pos = a[j] ? pa++ : pi++;
            cp[tid * 8 + j] = pos;
            bbp[pos] = a[j] ? 0.f : -1.44269504e10f;
        }
        if (tid == 0) nkg[b] = nk;
        return;
    }
    // weight transpose: matrix zi, 64x64 tile (tr,tc)
    const int zi = bx >> 8, t = bx & 255, tr = t >> 4, tc = t & 15;
    const float* src = (zi == 0) ? w0 : (zi == 1) ? w1 : (zi == 2) ? w2 : w3;
    u16* d = wt_dst + (size_t)zi * Dm * Dm;
    {
        int r = tid >> 2, cq = (tid & 3) * 16;
        const float* sp = src + (size_t)(tr * 64 + r) * Dm + tc * 64 + cq;
#pragma unroll
        for (int j = 0; j < 4; j++) {
            float4 vv = *(const float4*)(sp + j * 4);
            tl[r * 65 + cq + j * 4 + 0] = vv.x;
            tl[r * 65 + cq + j * 4 + 1] = vv.y;
            tl[r * 65 + cq + j * 4 + 2] = vv.z;
            tl[r * 65 + cq + j * 4 + 3] = vv.w;
        }
    }
    __syncthreads();
    {
        int rr = tid >> 2, cc = (tid & 3) * 16;
        u16* dp = d + (size_t)(tc * 64 + rr) * Dm + tr * 64 + cc;
        u32 px[8];
#pragma unroll
        for (int j = 0; j < 8; j++)
            px[j] = pack_bf16(tl[(cc + 2 * j) * 65 + rr], tl[(cc + 2 * j + 1) * 65 + rr]);
        *(uint4*)dp       = make_uint4(px[0], px[1], px[2], px[3]);
        *(uint4*)(dp + 8) = make_uint4(px[4], px[5], px[6], px[7]);
    }
}

// ---------------------------------------------------------------------------
// GEMM core A (m97 structure): C[128 x 128] = A[128xK] @ B[128 x K]^T,
// K=1024, BK=64. 256 thr = 4 waves (2m x 2n), wave tile 64x64, acc[4][4].
// LDS 32 KB. global_load_lds staging, XOR-swizzled tiles.
// ---------------------------------------------------------------------------
__device__ __forceinline__ void gemm_core_128128(
    const u16* __restrict__ Ab, const u16* __restrict__ Bb,
    u16* As, u16* Bs, f32x4 (&acc)[4][4])
{
    const int tid = threadIdx.x, lane = tid & 63;
    const int wm = (tid >> 7) & 1, wn = (tid >> 6) & 1;
    const int frow = lane & 15, quad = lane >> 4;

#pragma unroll
    for (int mi = 0; mi < 4; mi++)
#pragma unroll
        for (int ni = 0; ni < 4; ni++) acc[mi][ni] = (f32x4){0.f, 0.f, 0.f, 0.f};

    for (int k0 = 0; k0 < 1024; k0 += 64) {
#pragma unroll
        for (int i = 0; i < 4; i++) {
            int id = tid + i * 256, r = id >> 3, c = id & 7;
            gll16(Ab + (size_t)r * 1024 + k0 + (c ^ swz(r)) * 8, As + (size_t)id * 8);
        }
#pragma unroll
        for (int i = 0; i < 4; i++) {
            int id = tid + i * 256, r = id >> 3, c = id & 7;
            gll16(Bb + (size_t)r * 1024 + k0 + (c ^ swz(r)) * 8, Bs + (size_t)id * 8);
        }
        __syncthreads();
#pragma unroll
        for (int ks = 0; ks < 2; ks++) {
            bf16x8 af[4], bfr[4];
#pragma unroll
            for (int mi = 0; mi < 4; mi++) {
                int r = wm * 64 + mi * 16 + frow;
                af[mi] = lds_frag(As + r * 64 + ((ks * 4 + quad) ^ swz(r)) * 8);
            }
#pragma unroll
            for (int ni = 0; ni < 4; ni++) {
                int r = wn * 64 + ni * 16 + frow;
                bfr[ni] = lds_frag(Bs + r * 64 + ((ks * 4 + quad) ^ swz(r)) * 8);
            }
#pragma unroll
            for (int mi = 0; mi < 4; mi++)
#pragma unroll
                for (int ni = 0; ni < 4; ni++)
                    acc[mi][ni] = __builtin_amdgcn_mfma_f32_16x16x32_bf16(
                        af[mi], bfr[ni], acc[mi][ni], 0, 0, 0);
        }
        __syncthreads();
    }
}

// ---------------------------------------------------------------------------
// GEMM core B (small tile, for oproj where N=1024 would give 1 block/CU
// with the 128x128 tile): C[128 x 64] = A[128xK] @ B[64 x K]^T.
// ---------------------------------------------------------------------------
__device__ __forceinline__ void gemm_core_12864(
    const u16* __restrict__ Ab, const u16* __restrict__ Bb,
    u16* As, u16* Bs, f32x4 (&acc)[4][2])
{
    const int tid = threadIdx.x, lane = tid & 63;
    const int wm = (tid >> 7) & 1, wn = (tid >> 6) & 1;
    const int frow = lane & 15, quad = lane >> 4;

#pragma unroll
    for (int mi = 0; mi < 4; mi++)
#pragma unroll
        for (int ni = 0; ni < 2; ni++) acc[mi][ni] = (f32x4){0.f, 0.f, 0.f, 0.f};

    for (int k0 = 0; k0 < 1024; k0 += 64) {
#pragma unroll
        for (int i = 0; i < 4; i++) {
            int id = tid + i * 256, r = id >> 3, c = id & 7;
            gll16(Ab + (size_t)r * 1024 + k0 + (c ^ swz(r)) * 8, As + (size_t)id * 8);
        }
#pragma unroll
        for (int i = 0; i < 2; i++) {
            int id = tid + i * 256, r = id >> 3, c = id & 7;
            gll16(Bb + (size_t)r * 1024 + k0 + (c ^ swz(r)) * 8, Bs + (size_t)id * 8);
        }
        __syncthreads();
#pragma unroll
        for (int ks = 0; ks < 2; ks++) {
            bf16x8 af[4], bfr[2];
#pragma unroll
            for (int mi = 0; mi < 4; mi++) {
                int r = wm * 64 + mi * 16 + frow;
                af[mi] = lds_frag(As + r * 64 + ((ks * 4 + quad) ^ swz(r)) * 8);
            }
#pragma unroll
            for (int ni = 0; ni < 2; ni++) {
                int r = wn * 32 + ni * 16 + frow;
                bfr[ni] = lds_frag(Bs + r * 64 + ((ks * 4 + quad) ^ swz(r)) * 8);
            }
#pragma unroll
            for (int mi = 0; mi < 4; mi++)
#pragma unroll
                for (int ni = 0; ni < 2; ni++)
                    acc[mi][ni] = __builtin_amdgcn_mfma_f32_16x16x32_bf16(
                        af[mi], bfr[ni], acc[mi][ni], 0, 0, 0);
        }
        __syncthreads();
    }
}

// ---------------------------------------------------------------------------
// Kernel 2: QKV projections, 128x128 tiles, 256 blocks per z (3/CU total).
// z=0: Q->[B,H,S,DK]; z=1: K->[B,H,comp(s),DK] (COMPACTED rows);
// z=2: swapped operands -> V'^T [B,H,DK,sp(comp(s))] (compacted, keys
// bit2/3-swapped so PV B-operand is register-natural).
// ---------------------------------------------------------------------------
__global__ __launch_bounds__(256, 3) void mha_proj_qkv(
    const u16* __restrict__ Qb, const u16* __restrict__ Kb, const u16* __restrict__ Vb,
    const u16* __restrict__ Wqt, const u16* __restrict__ Wkt, const u16* __restrict__ Wvt,
    const float* __restrict__ bq, const float* __restrict__ bk, const float* __restrict__ bv,
    const int* __restrict__ comp,
    u16* __restrict__ Qh, u16* __restrict__ Kh, u16* __restrict__ Vt)
{
    __shared__ __align__(16) u16 As[128 * 64];
    __shared__ __align__(16) u16 Bs[128 * 64];
    const int z = blockIdx.z, bx = blockIdx.x;
    const u16* Ab; const u16* Bb; const float* bias;
    int m0, n0;
    if (z < 2) {
        m0 = (bx & 31) * 128;        // 32 m-tiles minor: XCD = m_t%8, tokens clustered
        n0 = (bx >> 5) * 128;        // 8 n-tiles
        Ab = ((z == 0) ? Qb : Kb) + (size_t)m0 * Dm;
        Bb = ((z == 0) ? Wqt : Wkt) + (size_t)n0 * Dm;
        bias = (z == 0) ? bq : bk;
    } else {
        m0 = (bx >> 5) * 128;        // 8 m-tiles (outdim)
        n0 = (bx & 31) * 128;        // 32 n-tiles minor: XCD = n_t%8, Vb tokens clustered
        Ab = Wvt + (size_t)m0 * Dm;
        Bb = Vb + (size_t)n0 * Dm;
        bias = bv;
    }

    f32x4 acc[4][4];
    gemm_core_128128(Ab, Bb, As, Bs, acc);

    const int tid = threadIdx.x, lane = tid & 63;
    const int wm = (tid >> 7) & 1, wn = (tid >> 6) & 1;
    const int frow = lane & 15, quad = lane >> 4;
    u16* dstq = (z == 0) ? Qh : Kh;
#pragma unroll
    for (int mi = 0; mi < 4; mi++)
#pragma unroll
        for (int ni = 0; ni < 4; ni++)
#pragma unroll
            for (int r = 0; r < 4; r++) {
                int i = m0 + wm * 64 + mi * 16 + quad * 4 + r;
                int j = n0 + wn * 64 + ni * 16 + frow;
                if (z < 2) {
                    float val = acc[mi][ni][r] + bias[j];
                    int b = i >> 11, s = i & (Sq - 1);
                    int h = j >> 6, dk = j & (DK - 1);
                    int srow = (z == 1) ? comp[b * Sq + s] : s;
                    dstq[((size_t)(b * Hn + h) * Sq + srow) * DK + dk] = f2bf(val);
                } else {
                    float val = acc[mi][ni][r] + bias[i];
                    int h = i >> 6, dk = i & (DK - 1);
                    int bj = j >> 11, s = j & (Sq - 1);
                    int cs = comp[bj * Sq + s];
                    int sp = (cs & ~12) | ((cs & 4) << 1) | ((cs & 8) >> 1);  // swap bits 2,3
                    Vt[((size_t)(bj * Hn + h) * DK + dk) * Sq + sp] = f2bf(val);
                }
            }
}

// ---------------------------------------------------------------------------
// Kernel 3: flash attention over COMPACTED keys. R4-MEASURED body (VGPR 56,
// WRITE 8192 KB = no spill, 45.4 us) — restored byte-for-byte after R5/R6
// variants spilled (R5: 4q-groups, +34 MB scratch; R6: 256-key tiles +
// runtime nt, +150 MB scratch). This body is the only compaction-aware
// attn measured spill-free; treat its structure as frozen unless a future
// change is verified against WRITE_SIZE==8192.
// 512 thr = 8 waves = 2 q-groups (32q) x 4 key-parities (32 keys each of a
// 128-key tile). Single-buffered K/V staging with PRECOMPUTED per-thread
// staging pointers (4 gll16/thread/tile); runtime nt = ceil(nk/128); masked
// keys parked past nk with -inf bias (exp2 -> 0). No-max exp2 softmax, P
// register-resident, setprio(1) around MFMA, 2-barrier tree combine.
// __launch_bounds__(512,4): cap 128 regs. DO NOT raise the min-waves arg
// ((512,8) forced 64-cap -> catastrophic spill, R3).
// ---------------------------------------------------------------------------
__global__ __launch_bounds__(512, 4) void mha_attn(
    const u16* __restrict__ Qh, const u16* __restrict__ Kh, const u16* __restrict__ Vt,
    const float* __restrict__ biasg, const int* __restrict__ nkg,
    u16* __restrict__ X)
{
    const int bh = blockIdx.x;                 // b*16+h -> XCD = bh%8
    const int b = bh >> 4;
    const int q0 = blockIdx.y * 64;
    const int tid = threadIdx.x, lane = tid & 63, w = tid >> 6;
    const int wq = w & 1, p = w >> 1;          // q-group, key-parity 0..3
    const int qc = lane & 31, half = lane >> 5;
    constexpr float C2 = 0.125f * 1.44269504f; // 1/sqrt(DK) * log2(e)

    // single shared block: K tile 16 KB + V tile 16 KB (aliased as the
    // 32 KB combine scratch after the k-loop)
    __shared__ __align__(16) u16 SB[128 * 64 + 64 * 128];
    __shared__ float lsl[256];
    u16* Ks = SB;
    u16* Vs = SB + 128 * 64;

    const u16* Qp = Qh + (size_t)bh * Sq * DK;
    const u16* Kp = Kh + (size_t)bh * Sq * DK;
    const u16* Vp = Vt + (size_t)bh * DK * Sq;
    const float* bp = biasg + b * Sq;
    const int nk = nkg[b];
    const int nt = (nk + 127) >> 7;            // tiles of 128 compacted keys

    // Q B-frags direct from global (once): lane n=qc; k = kc*16 + half*8 + j
    bf16x8 qf[4];
    {
        const u16* qrow = Qp + (size_t)(q0 + wq * 32 + qc) * DK + half * 8;
#pragma unroll
        for (int kc = 0; kc < 4; kc++) qf[kc] = gfrag(qrow + kc * 16);
    }

    // staging precompute: 4 gll16 per tile (2 K + 2 V), 32 KB/tile
    const int idA = tid, idB = tid + 512;
    const u16* ksA = Kp + (size_t)(idA >> 3) * DK + ((idA & 7) ^ swz(idA >> 3)) * 8;
    const u16* ksB = Kp + (size_t)(idB >> 3) * DK + ((idB & 7) ^ swz(idB >> 3)) * 8;
    const u16* vsA = Vp + (size_t)(idA >> 4) * Sq + (((idA & 15) ^ ((idA >> 4) & 15)) * 8);
    const u16* vsB = Vp + (size_t)(idB >> 4) * Sq + (((idB & 15) ^ ((idB >> 4) & 15)) * 8);
    u16* kdA = Ks + idA * 8;
    u16* kdB = Ks + idB * 8;
    u16* vdA = Vs + idA * 8;
    u16* vdB = Vs + idB * 8;

    auto stage = [&](int kb) {
        gll16(ksA + (size_t)kb * DK, kdA);
        gll16(ksB + (size_t)kb * DK, kdB);
        gll16(vsA + kb, vdA);
        gll16(vsB + kb, vdB);
    };

    // fragment LDS offsets (loop-invariant)
    const int kr = p * 32 + qc;
    int kfo[4];
#pragma unroll
    for (int kc = 0; kc < 4; kc++)
        kfo[kc] = kr * 64 + (((kc * 2 + half) ^ swz(kr)) * 8);
    int vfo0[2], vfo1[2];
#pragma unroll
    for (int kc = 0; kc < 2; kc++) {
        int ch = p * 4 + kc * 2 + half;
        vfo0[kc] = qc * 128 + ((ch ^ (qc & 15)) * 8);
        vfo1[kc] = (32 + qc) * 128 + ((ch ^ (qc & 15)) * 8);
    }
    const float* bpw = bp + p * 32 + 4 * half;

    float l_l = 0.f;
    f32x16 o0, o1;
#pragma unroll
    for (int i = 0; i < 16; i++) { o0[i] = 0.f; o1[i] = 0.f; }

    for (int it = 0; it < nt; it++) {
        stage(it * 128);
        __syncthreads();                       // drain vmcnt -> tile ready

        // ---- S^T = K Q^T on this wave's 32-key slice ----
        f32x16 sT;
#pragma unroll
        for (int i = 0; i < 16; i++) sT[i] = 0.f;
        __builtin_amdgcn_s_setprio(1);
#pragma unroll
        for (int kc = 0; kc < 4; kc++) {
            bf16x8 ka = lds_frag(Ks + kfo[kc]);
            sT = __builtin_amdgcn_mfma_f32_32x32x16_bf16(ka, qf[kc], sT, 0, 0, 0);
        }
        __builtin_amdgcn_s_setprio(0);

        // ---- no-max exp2 softmax; C row(key) = (r&3)+8*(r>>2)+4*half ----
        const int kb = it * 128;
        float t[16], rs = 0.f;
#pragma unroll
        for (int g = 0; g < 4; g++) {
            float4 mb = *(const float4*)(bpw + kb + 8 * g);
#pragma unroll
            for (int r = 0; r < 4; r++) {
                float bb = (r == 0) ? mb.x : (r == 1) ? mb.y : (r == 2) ? mb.z : mb.w;
                float a = __builtin_amdgcn_exp2f(fmaf(sT[g * 4 + r], C2, bb));
                t[g * 4 + r] = a; rs += a;
            }
        }
        l_l += rs;

        // ---- pack P (register-resident; slot = key w/ bits2,3 swapped) ----
        u32 pk[8];
#pragma unroll
        for (int i = 0; i < 8; i++) pk[i] = pack_bf16(t[2 * i], t[2 * i + 1]);

        // ---- O^T += V P^T (2 MFMAs of k=16 per d-half) ----
        __builtin_amdgcn_s_setprio(1);
#pragma unroll
        for (int kc = 0; kc < 2; kc++) {
            bf16x8 pf = __builtin_bit_cast(bf16x8,
                make_uint4(pk[4 * kc], pk[4 * kc + 1], pk[4 * kc + 2], pk[4 * kc + 3]));
            bf16x8 va0 = lds_frag(Vs + vfo0[kc]);
            bf16x8 va1 = lds_frag(Vs + vfo1[kc]);
            o0 = __builtin_amdgcn_mfma_f32_32x32x16_bf16(va0, pf, o0, 0, 0, 0);
            o1 = __builtin_amdgcn_mfma_f32_32x32x16_bf16(va1, pf, o1, 0, 0, 0);
        }
        __builtin_amdgcn_s_setprio(0);
        __syncthreads();                       // all reads done before re-stage
    }

    // ---- tree combine of 4 key-parity partials (2 barriers) ----
    l_l += __shfl_xor(l_l, 32);
    float* fcb = (float*)SB;                 // 32 KB = 4 segs x 8 KB
    if (p >= 2) {                            // round 1 write: p=2->seg(wq,0), p=3->seg(wq,1)
        float* fc = fcb + (size_t)(wq * 2 + (p & 1)) * 2048;
#pragma unroll
        for (int r = 0; r < 16; r++) fc[r * 64 + lane] = o0[r];
#pragma unroll
        for (int r = 0; r < 16; r++) fc[(16 + r) * 64 + lane] = o1[r];
        lsl[(wq * 2 + (p & 1)) * 64 + lane] = l_l;
    }
    __syncthreads();
    if (p < 2) {                             // round 1 add (parallel on p=0,1)
        float* fc = fcb + (size_t)(wq * 2 + p) * 2048;
#pragma unroll
        for (int r = 0; r < 16; r++) o0[r] += fc[r * 64 + lane];
#pragma unroll
        for (int r = 0; r < 16; r++) o1[r] += fc[(16 + r) * 64 + lane];
        l_l += lsl[(wq * 2 + p) * 64 + lane];
    }
    if (p == 1) {                            // round 2 write (same seg it just read)
        float* fc = fcb + (size_t)(wq * 2 + 1) * 2048;
#pragma unroll
        for (int r = 0; r < 16; r++) fc[r * 64 + lane] = o0[r];
#pragma unroll
        for (int r = 0; r < 16; r++) fc[(16 + r) * 64 + lane] = o1[r];
        lsl[(wq * 2 + 1) * 64 + lane] = l_l;
    }
    __syncthreads();
    if (p == 0) {
        float* fc = fcb + (size_t)(wq * 2 + 1) * 2048;
#pragma unroll
        for (int r = 0; r < 16; r++) o0[r] += fc[r * 64 + lane];
#pragma unroll
        for (int r = 0; r < 16; r++) o1[r] += fc[(16 + r) * 64 + lane];
        l_l += lsl[(wq * 2 + 1) * 64 + lane];
        float inv = 1.0f / l_l;
        const int qg = q0 + wq * 32 + qc;
        u16* Xp = X + (size_t)(b * Sq + qg) * Dm + (bh & 15) * DK;
#pragma unroll
        for (int g = 0; g < 4; g++) {
            *(uint2*)&Xp[8 * g + 4 * half] =
                make_uint2(pack_bf16(o0[g * 4 + 0] * inv, o0[g * 4 + 1] * inv),
                           pack_bf16(o0[g * 4 + 2] * inv, o0[g * 4 + 3] * inv));
            *(uint2*)&Xp[32 + 8 * g + 4 * half] =
                make_uint2(pack_bf16(o1[g * 4 + 0] * inv, o1[g * 4 + 1] * inv),
                           pack_bf16(o1[g * 4 + 2] * inv, o1[g * 4 + 3] * inv));
        }
    }
}

// ---------------------------------------------------------------------------
// Kernel 4: out = X @ Wo + bo (fp32). 128x64 tiles, m-major -> 512 blocks
// (2 blocks/CU; the 128x128 tile would leave 1/CU here).
// ---------------------------------------------------------------------------
__global__ __launch_bounds__(256) void mha_oproj(
    const u16* __restrict__ X, const u16* __restrict__ Wot,
    const float* __restrict__ bo, float* __restrict__ out)
{
    __shared__ __align__(16) u16 As[128 * 64];
    __shared__ __align__(16) u16 Bs[64 * 64];
    const int bx = blockIdx.x;
    const int m0 = (bx & 31) * 128, n0 = (bx >> 5) * 64;
    f32x4 acc[4][2];
    gemm_core_12864(X + (size_t)m0 * Dm, Wot + (size_t)n0 * Dm, As, Bs, acc);
    const int tid = threadIdx.x, lane = tid & 63;
    const int wm = (tid >> 7) & 1, wn = (tid >> 6) & 1;
    const int frow = lane & 15, quad = lane >> 4;
#pragma unroll
    for (int mi = 0; mi < 4; mi++)
#pragma unroll
        for (int ni = 0; ni < 2; ni++)
#pragma unroll
            for (int r = 0; r < 4; r++) {
                int m = m0 + wm * 64 + mi * 16 + quad * 4 + r;
                int n = n0 + wn * 32 + ni * 16 + frow;
                out[(size_t)m * Dm + n] = acc[mi][ni][r] + bo[n];
            }
}

// ---------------------------------------------------------------------------
extern "C" void kernel_launch(void* const* d_in, const int* in_sizes, int n_in,
                              void* d_out, int out_size, void* d_ws, size_t ws_size,
                              hipStream_t stream)
{
    const float* qin  = (const float*)d_in[0];
    const float* kin  = (const float*)d_in[1];
    const float* vin  = (const float*)d_in[2];
    const int*   mask = (const int*)d_in[3];
    const float* Wq   = (const float*)d_in[4];
    const float* bq   = (const float*)d_in[5];
    const float* Wk   = (const float*)d_in[6];
    const float* bk   = (const float*)d_in[7];
    const float* Wv   = (const float*)d_in[8];
    const float* bv   = (const float*)d_in[9];
    const float* Wo   = (const float*)d_in[10];
    const float* bo   = (const float*)d_in[11];
    float* out = (float*)d_out;

    u16* ws = (u16*)d_ws;
    const size_t MW = (size_t)Dm * Dm;
    const size_t MT = (size_t)Bz * Sq * Dm;
    u16* Wqt = ws;
    u16* Wkt = ws + MW;
    u16* Wvt = ws + 2 * MW;
    u16* Wot = ws + 3 * MW;
    u16* Qb  = ws + 4 * MW;
    u16* Kb  = Qb + MT;
    u16* Vb  = Kb + MT;
    u16* Qh  = Vb + MT;
    u16* Kh  = Qh + MT;
    u16* Vt  = Kh + MT;
    float* biasg = (float*)(Vt + MT);          // 16 KB (compacted bias)
    int*   compg = (int*)(biasg + Bz * Sq);    // 16 KB (key -> compact pos)
    int*   nkg   = (int*)(compg + Bz * Sq);    // 2 ints (#active keys per b)
    u16* X   = Qb;                             // Qb dead after proj

    hipLaunchKernelGGL(mha_prep, dim3(2048, 1, 4), dim3(256), 0, stream,
                       qin, kin, vin, Wq, Wk, Wv, Wo, mask, Qb, Wqt, biasg, compg, nkg);
    hipLaunchKernelGGL(mha_proj_qkv, dim3(256, 1, 3), dim3(256), 0, stream,
                       Qb, Kb, Vb, Wqt, Wkt, Wvt, bq, bk, bv, compg, Qh, Kh, Vt);
    hipLaunchKernelGGL(mha_attn, dim3(32, 32), dim3(512), 0, stream,
                       Qh, Kh, Vt, biasg, nkg, X);
    hipLaunchKernelGGL(mha_oproj, dim3(512), dim3(256), 0, stream,
                       X, Wot, bo, out);
}

// Round 8
// 217.487 us; speedup vs baseline: 1.2676x; 1.0417x over previous
//
#include <hip/hip_runtime.h>
#include <hip/hip_bf16.h>

typedef unsigned short u16;
typedef unsigned int u32;
typedef __attribute__((ext_vector_type(8))) __bf16 bf16x8;
typedef __attribute__((ext_vector_type(4))) float f32x4;
typedef __attribute__((ext_vector_type(16))) float f32x16;

constexpr int Bz = 2, Sq = 2048, Dm = 1024, Hn = 16, DK = 64;

__device__ __forceinline__ u16 f2bf(float f) {
    u32 u = __builtin_bit_cast(u32, f);
    return (u16)((u + 0x7FFFu + ((u >> 16) & 1u)) >> 16);   // RNE
}

__device__ __forceinline__ u32 pack_bf16(float a, float b) {
#if __has_builtin(__builtin_amdgcn_cvt_pk_bf16_f32)
    return __builtin_bit_cast(u32, __builtin_amdgcn_cvt_pk_bf16_f32(a, b));
#else
    return (u32)f2bf(a) | ((u32)f2bf(b) << 16);
#endif
}

__device__ __forceinline__ bf16x8 lds_frag(const u16* p) {
    return __builtin_bit_cast(bf16x8, *(const uint4*)p);
}
__device__ __forceinline__ bf16x8 gfrag(const u16* p) {
    return __builtin_bit_cast(bf16x8, *(const uint4*)p);
}
__device__ __forceinline__ int swz(int r) { return (r ^ (r >> 3)) & 7; }

// async global->LDS, 16B per lane; dest = wave-uniform base + lane*16
__device__ __forceinline__ void gll16(const u16* g, u16* l) {
    __builtin_amdgcn_global_load_lds(
        (const __attribute__((address_space(1))) void*)g,
        (__attribute__((address_space(3))) void*)l, 16, 0, 0);
}

// ---------------------------------------------------------------------------
// Kernel 1 (fused prep): z<3: cast q/k/v fp32->bf16. z==3:
//   bx<1024     : transpose+cast the 4 weights (64x64 tiles) -> Wt [N,K] bf16
//   bx==1024/5  : per-batch key compaction scan: comp[s] = compacted position
//                 (active keys mask==0 -> front ranks; masked keys parked at
//                 tail), bias (compacted) 0 / -1e10*log2e, nk[b] = #active.
// ---------------------------------------------------------------------------
__global__ __launch_bounds__(256) void mha_prep(
    const float* __restrict__ q, const float* __restrict__ k,
    const float* __restrict__ v,
    const float* __restrict__ w0, const float* __restrict__ w1,
    const float* __restrict__ w2, const float* __restrict__ w3,
    const int* __restrict__ mask,
    u16* __restrict__ qkv_dst, u16* __restrict__ wt_dst,
    float* __restrict__ biasg, int* __restrict__ compg, int* __restrict__ nkg)
{
    __shared__ float tl[64 * 65];
    __shared__ int sc[256];
    const int z = blockIdx.z, tid = threadIdx.x;
    if (z < 3) {
        const float* s = (z == 0) ? q : (z == 1) ? k : v;
        u16* d = qkv_dst + (size_t)z * 4 * 1024 * 1024;
        size_t i = ((size_t)blockIdx.x * 256 + tid) * 8;
        float4 a = *(const float4*)(s + i);
        float4 b = *(const float4*)(s + i + 4);
        *(uint4*)(d + i) = make_uint4(pack_bf16(a.x, a.y), pack_bf16(a.z, a.w),
                                      pack_bf16(b.x, b.y), pack_bf16(b.z, b.w));
        return;
    }
    const int bx = blockIdx.x;
    if (bx >= 1026) return;
    if (bx >= 1024) {   // compaction scan for batch b
        const int b = bx - 1024;
        const int* mp = mask + b * Sq;
        int4 m0_ = ((const int4*)mp)[tid * 2];
        int4 m1_ = ((const int4*)mp)[tid * 2 + 1];
        int a[8];
        a[0] = (m0_.x == 0); a[1] = (m0_.y == 0); a[2] = (m0_.z == 0); a[3] = (m0_.w == 0);
        a[4] = (m1_.x == 0); a[5] = (m1_.y == 0); a[6] = (m1_.z == 0); a[7] = (m1_.w == 0);
        int cnt = 0;
#pragma unroll
        for (int j = 0; j < 8; j++) cnt += a[j];
        sc[tid] = cnt;
        __syncthreads();
        for (int off = 1; off < 256; off <<= 1) {
            int u = (tid >= off) ? sc[tid - off] : 0;
            int vv = sc[tid];
            __syncthreads();
            sc[tid] = vv + u;
            __syncthreads();
        }
        const int incl = sc[tid];
        const int nk = sc[255];
        int pa = incl - cnt;            // actives before my 8 elems
        int pi = nk + tid * 8 - pa;     // nk + inactives before
        int* cp = compg + b * Sq;
        float* bbp = biasg + b * Sq;
#pragma unroll
        for (int j = 0; j < 8; j++) {
            int pos = a[j] ? pa++ : pi++;
            cp[tid * 8 + j] = pos;
            bbp[pos] = a[j] ? 0.f : -1.44269504e10f;
        }
        if (tid == 0) nkg[b] = nk;
        return;
    }
    // weight transpose: matrix zi, 64x64 tile (tr,tc)
    const int zi = bx >> 8, t = bx & 255, tr = t >> 4, tc = t & 15;
    const float* src = (zi == 0) ? w0 : (zi == 1) ? w1 : (zi == 2) ? w2 : w3;
    u16* d = wt_dst + (size_t)zi * Dm * Dm;
    {
        int r = tid >> 2, cq = (tid & 3) * 16;
        const float* sp = src + (size_t)(tr * 64 + r) * Dm + tc * 64 + cq;
#pragma unroll
        for (int j = 0; j < 4; j++) {
            float4 vv = *(const float4*)(sp + j * 4);
            tl[r * 65 + cq + j * 4 + 0] = vv.x;
            tl[r * 65 + cq + j * 4 + 1] = vv.y;
            tl[r * 65 + cq + j * 4 + 2] = vv.z;
            tl[r * 65 + cq + j * 4 + 3] = vv.w;
        }
    }
    __syncthreads();
    {
        int rr = tid >> 2, cc = (tid & 3) * 16;
        u16* dp = d + (size_t)(tc * 64 + rr) * Dm + tr * 64 + cc;
        u32 px[8];
#pragma unroll
        for (int j = 0; j < 8; j++)
            px[j] = pack_bf16(tl[(cc + 2 * j) * 65 + rr], tl[(cc + 2 * j + 1) * 65 + rr]);
        *(uint4*)dp       = make_uint4(px[0], px[1], px[2], px[3]);
        *(uint4*)(dp + 8) = make_uint4(px[4], px[5], px[6], px[7]);
    }
}

// ---------------------------------------------------------------------------
// GEMM core A (m97 structure): C[128 x 128] = A[128xK] @ B[128 x K]^T,
// K=1024, BK=64. 256 thr = 4 waves (2m x 2n), wave tile 64x64, acc[4][4].
// LDS 32 KB. global_load_lds staging, XOR-swizzled tiles.
// ---------------------------------------------------------------------------
__device__ __forceinline__ void gemm_core_128128(
    const u16* __restrict__ Ab, const u16* __restrict__ Bb,
    u16* As, u16* Bs, f32x4 (&acc)[4][4])
{
    const int tid = threadIdx.x, lane = tid & 63;
    const int wm = (tid >> 7) & 1, wn = (tid >> 6) & 1;
    const int frow = lane & 15, quad = lane >> 4;

#pragma unroll
    for (int mi = 0; mi < 4; mi++)
#pragma unroll
        for (int ni = 0; ni < 4; ni++) acc[mi][ni] = (f32x4){0.f, 0.f, 0.f, 0.f};

    for (int k0 = 0; k0 < 1024; k0 += 64) {
#pragma unroll
        for (int i = 0; i < 4; i++) {
            int id = tid + i * 256, r = id >> 3, c = id & 7;
            gll16(Ab + (size_t)r * 1024 + k0 + (c ^ swz(r)) * 8, As + (size_t)id * 8);
        }
#pragma unroll
        for (int i = 0; i < 4; i++) {
            int id = tid + i * 256, r = id >> 3, c = id & 7;
            gll16(Bb + (size_t)r * 1024 + k0 + (c ^ swz(r)) * 8, Bs + (size_t)id * 8);
        }
        __syncthreads();
#pragma unroll
        for (int ks = 0; ks < 2; ks++) {
            bf16x8 af[4], bfr[4];
#pragma unroll
            for (int mi = 0; mi < 4; mi++) {
                int r = wm * 64 + mi * 16 + frow;
                af[mi] = lds_frag(As + r * 64 + ((ks * 4 + quad) ^ swz(r)) * 8);
            }
#pragma unroll
            for (int ni = 0; ni < 4; ni++) {
                int r = wn * 64 + ni * 16 + frow;
                bfr[ni] = lds_frag(Bs + r * 64 + ((ks * 4 + quad) ^ swz(r)) * 8);
            }
#pragma unroll
            for (int mi = 0; mi < 4; mi++)
#pragma unroll
                for (int ni = 0; ni < 4; ni++)
                    acc[mi][ni] = __builtin_amdgcn_mfma_f32_16x16x32_bf16(
                        af[mi], bfr[ni], acc[mi][ni], 0, 0, 0);
        }
        __syncthreads();
    }
}

// ---------------------------------------------------------------------------
// GEMM core B (small tile, for oproj where N=1024 would give 1 block/CU
// with the 128x128 tile): C[128 x 64] = A[128xK] @ B[64 x K]^T.
// ---------------------------------------------------------------------------
__device__ __forceinline__ void gemm_core_12864(
    const u16* __restrict__ Ab, const u16* __restrict__ Bb,
    u16* As, u16* Bs, f32x4 (&acc)[4][2])
{
    const int tid = threadIdx.x, lane = tid & 63;
    const int wm = (tid >> 7) & 1, wn = (tid >> 6) & 1;
    const int frow = lane & 15, quad = lane >> 4;

#pragma unroll
    for (int mi = 0; mi < 4; mi++)
#pragma unroll
        for (int ni = 0; ni < 2; ni++) acc[mi][ni] = (f32x4){0.f, 0.f, 0.f, 0.f};

    for (int k0 = 0; k0 < 1024; k0 += 64) {
#pragma unroll
        for (int i = 0; i < 4; i++) {
            int id = tid + i * 256, r = id >> 3, c = id & 7;
            gll16(Ab + (size_t)r * 1024 + k0 + (c ^ swz(r)) * 8, As + (size_t)id * 8);
        }
#pragma unroll
        for (int i = 0; i < 2; i++) {
            int id = tid + i * 256, r = id >> 3, c = id & 7;
            gll16(Bb + (size_t)r * 1024 + k0 + (c ^ swz(r)) * 8, Bs + (size_t)id * 8);
        }
        __syncthreads();
#pragma unroll
        for (int ks = 0; ks < 2; ks++) {
            bf16x8 af[4], bfr[2];
#pragma unroll
            for (int mi = 0; mi < 4; mi++) {
                int r = wm * 64 + mi * 16 + frow;
                af[mi] = lds_frag(As + r * 64 + ((ks * 4 + quad) ^ swz(r)) * 8);
            }
#pragma unroll
            for (int ni = 0; ni < 2; ni++) {
                int r = wn * 32 + ni * 16 + frow;
                bfr[ni] = lds_frag(Bs + r * 64 + ((ks * 4 + quad) ^ swz(r)) * 8);
            }
#pragma unroll
            for (int mi = 0; mi < 4; mi++)
#pragma unroll
                for (int ni = 0; ni < 2; ni++)
                    acc[mi][ni] = __builtin_amdgcn_mfma_f32_16x16x32_bf16(
                        af[mi], bfr[ni], acc[mi][ni], 0, 0, 0);
        }
        __syncthreads();
    }
}

// ---------------------------------------------------------------------------
// Kernel 2: QKV projections, 128x128 tiles, 256 blocks per z (3/CU total).
// z=0: Q->[B,H,S,DK]; z=1: K->[B,H,comp(s),DK] (COMPACTED rows);
// z=2: swapped operands -> V'^T [B,H,DK,sp(comp(s))] (compacted, keys
// bit2/3-swapped so PV B-operand is register-natural).
// ---------------------------------------------------------------------------
__global__ __launch_bounds__(256, 3) void mha_proj_qkv(
    const u16* __restrict__ Qb, const u16* __restrict__ Kb, const u16* __restrict__ Vb,
    const u16* __restrict__ Wqt, const u16* __restrict__ Wkt, const u16* __restrict__ Wvt,
    const float* __restrict__ bq, const float* __restrict__ bk, const float* __restrict__ bv,
    const int* __restrict__ comp,
    u16* __restrict__ Qh, u16* __restrict__ Kh, u16* __restrict__ Vt)
{
    __shared__ __align__(16) u16 As[128 * 64];
    __shared__ __align__(16) u16 Bs[128 * 64];
    const int z = blockIdx.z, bx = blockIdx.x;
    const u16* Ab; const u16* Bb; const float* bias;
    int m0, n0;
    if (z < 2) {
        m0 = (bx & 31) * 128;        // 32 m-tiles minor: XCD = m_t%8, tokens clustered
        n0 = (bx >> 5) * 128;        // 8 n-tiles
        Ab = ((z == 0) ? Qb : Kb) + (size_t)m0 * Dm;
        Bb = ((z == 0) ? Wqt : Wkt) + (size_t)n0 * Dm;
        bias = (z == 0) ? bq : bk;
    } else {
        m0 = (bx >> 5) * 128;        // 8 m-tiles (outdim)
        n0 = (bx & 31) * 128;        // 32 n-tiles minor: XCD = n_t%8, Vb tokens clustered
        Ab = Wvt + (size_t)m0 * Dm;
        Bb = Vb + (size_t)n0 * Dm;
        bias = bv;
    }

    f32x4 acc[4][4];
    gemm_core_128128(Ab, Bb, As, Bs, acc);

    const int tid = threadIdx.x, lane = tid & 63;
    const int wm = (tid >> 7) & 1, wn = (tid >> 6) & 1;
    const int frow = lane & 15, quad = lane >> 4;
    u16* dstq = (z == 0) ? Qh : Kh;
#pragma unroll
    for (int mi = 0; mi < 4; mi++)
#pragma unroll
        for (int ni = 0; ni < 4; ni++)
#pragma unroll
            for (int r = 0; r < 4; r++) {
                int i = m0 + wm * 64 + mi * 16 + quad * 4 + r;
                int j = n0 + wn * 64 + ni * 16 + frow;
                if (z < 2) {
                    float val = acc[mi][ni][r] + bias[j];
                    int b = i >> 11, s = i & (Sq - 1);
                    int h = j >> 6, dk = j & (DK - 1);
                    int srow = (z == 1) ? comp[b * Sq + s] : s;
                    dstq[((size_t)(b * Hn + h) * Sq + srow) * DK + dk] = f2bf(val);
                } else {
                    float val = acc[mi][ni][r] + bias[i];
                    int h = i >> 6, dk = i & (DK - 1);
                    int bj = j >> 11, s = j & (Sq - 1);
                    int cs = comp[bj * Sq + s];
                    int sp = (cs & ~12) | ((cs & 4) << 1) | ((cs & 8) >> 1);  // swap bits 2,3
                    Vt[((size_t)(bj * Hn + h) * DK + dk) * Sq + sp] = f2bf(val);
                }
            }
}

// ---------------------------------------------------------------------------
// Kernel 3: flash attention over COMPACTED keys. Inner math = frozen R4
// body (the only spill-free compaction-aware variant: VGPR 56). Two changes
// vs R4, forming the T3/T4 counted-vmcnt pipeline:
//  (1) bias COMPUTED not loaded: after compaction bias = (key<nk ? 0:-inf),
//      2 VALU ops. Removes ALL vector-memory ops from the compute phase --
//      vmcnt is in-order, so the old in-loop biasg loads forced a full
//      vmcnt(0) drain of the staging prefetch mid-compute (why R2's dbuf
//      never paid).
//  (2) double-buffered staging with counted waits: stage tile t+1, then
//      s_waitcnt vmcnt(4) (tile t's 4 loads done, t+1's stay in flight
//      across the whole compute), sched_barrier(0) [rule #18], raw
//      s_barrier; trailing raw s_barrier protects re-staging. Last iter
//      vmcnt(0). LDS 2x32 KB + 1 KB -> 2 blocks/CU.
// SPILL GUARD: WRITE_SIZE must stay 8192 KB (X only). R5/R6 spills showed
// +26..150 MB scratch when this body's register budget is exceeded; if
// this round's WRITE_SIZE > 8192, revert to frozen R4 attn.
// __launch_bounds__(512,4): cap 128 regs. DO NOT raise the min-waves arg
// ((512,8) forced 64-cap -> catastrophic spill, R3).
// ---------------------------------------------------------------------------
__global__ __launch_bounds__(512, 4) void mha_attn(
    const u16* __restrict__ Qh, const u16* __restrict__ Kh, const u16* __restrict__ Vt,
    const int* __restrict__ nkg, u16* __restrict__ X)
{
    const int bh = blockIdx.x;                 // b*16+h -> XCD = bh%8
    const int b = bh >> 4;
    const int q0 = blockIdx.y * 64;
    const int tid = threadIdx.x, lane = tid & 63, w = tid >> 6;
    const int wq = w & 1, p = w >> 1;          // q-group, key-parity 0..3
    const int qc = lane & 31, half = lane >> 5;
    constexpr float C2 = 0.125f * 1.44269504f; // 1/sqrt(DK) * log2(e)

    // 2 buffers x (K tile 16 KB | V tile 16 KB); aliased as 32 KB combine
    // scratch after the k-loop. Per-buffer layout: [Ks 8192 u16][Vs 8192 u16].
    __shared__ __align__(16) u16 SB[2 * 16384];
    __shared__ float lsl[256];

    const u16* Qp = Qh + (size_t)bh * Sq * DK;
    const u16* Kp = Kh + (size_t)bh * Sq * DK;
    const u16* Vp = Vt + (size_t)bh * DK * Sq;
    const int nk = nkg[b];
    const int nt = (nk + 127) >> 7;            // tiles of 128 compacted keys

    // Q B-frags direct from global (once): lane n=qc; k = kc*16 + half*8 + j
    bf16x8 qf[4];
    {
        const u16* qrow = Qp + (size_t)(q0 + wq * 32 + qc) * DK + half * 8;
#pragma unroll
        for (int kc = 0; kc < 4; kc++) qf[kc] = gfrag(qrow + kc * 16);
    }

    // staging precompute: 4 gll16 per tile (2 K + 2 V), 32 KB/tile
    const int idA = tid, idB = tid + 512;
    const u16* ksA = Kp + (size_t)(idA >> 3) * DK + ((idA & 7) ^ swz(idA >> 3)) * 8;
    const u16* ksB = Kp + (size_t)(idB >> 3) * DK + ((idB & 7) ^ swz(idB >> 3)) * 8;
    const u16* vsA = Vp + (size_t)(idA >> 4) * Sq + (((idA & 15) ^ ((idA >> 4) & 15)) * 8);
    const u16* vsB = Vp + (size_t)(idB >> 4) * Sq + (((idB & 15) ^ ((idB >> 4) & 15)) * 8);
    u16* kdA = SB + idA * 8;
    u16* kdB = SB + idB * 8;
    u16* vdA = SB + 8192 + idA * 8;
    u16* vdB = SB + 8192 + idB * 8;

    auto stage = [&](int cur, int kb) {
        const int co = cur * 16384;
        gll16(ksA + (size_t)kb * DK, kdA + co);
        gll16(ksB + (size_t)kb * DK, kdB + co);
        gll16(vsA + kb, vdA + co);
        gll16(vsB + kb, vdB + co);
    };

    // fragment LDS offsets (loop-invariant, relative to buffer base)
    const int kr = p * 32 + qc;
    int kfo[4];
#pragma unroll
    for (int kc = 0; kc < 4; kc++)
        kfo[kc] = kr * 64 + (((kc * 2 + half) ^ swz(kr)) * 8);
    int vfo0[2], vfo1[2];
#pragma unroll
    for (int kc = 0; kc < 2; kc++) {
        int ch = p * 4 + kc * 2 + half;
        vfo0[kc] = qc * 128 + ((ch ^ (qc & 15)) * 8);
        vfo1[kc] = (32 + qc) * 128 + ((ch ^ (qc & 15)) * 8);
    }
    const int kbias = p * 32 + 4 * half;       // + kb + 8g + r = key index

    float l_l = 0.f;
    f32x16 o0, o1;
#pragma unroll
    for (int i = 0; i < 16; i++) { o0[i] = 0.f; o1[i] = 0.f; }

    stage(0, 0);
    for (int it = 0; it < nt; it++) {
        const int cur = it & 1;
        if (it + 1 < nt) {
            stage(cur ^ 1, (it + 1) * 128);
            asm volatile("s_waitcnt vmcnt(4)" ::: "memory");  // tile t done, t+1 in flight
        } else {
            asm volatile("s_waitcnt vmcnt(0)" ::: "memory");
        }
        __builtin_amdgcn_sched_barrier(0);
        __builtin_amdgcn_s_barrier();

        const u16* Kl = SB + cur * 16384;
        const u16* Vl = Kl + 8192;

        // ---- S^T = K Q^T on this wave's 32-key slice ----
        f32x16 sT;
#pragma unroll
        for (int i = 0; i < 16; i++) sT[i] = 0.f;
        __builtin_amdgcn_s_setprio(1);
#pragma unroll
        for (int kc = 0; kc < 4; kc++) {
            bf16x8 ka = lds_frag(Kl + kfo[kc]);
            sT = __builtin_amdgcn_mfma_f32_32x32x16_bf16(ka, qf[kc], sT, 0, 0, 0);
        }
        __builtin_amdgcn_s_setprio(0);

        // ---- no-max exp2 softmax; bias computed: key<nk ? 0 : -inf ----
        const int thr = nk - it * 128 - kbias; // key<nk  <=>  8g+r < thr
        float t[16], rs = 0.f;
#pragma unroll
        for (int g = 0; g < 4; g++) {
#pragma unroll
            for (int r = 0; r < 4; r++) {
                float bb = (8 * g + r < thr) ? 0.f : -1.44269504e10f;
                float a = __builtin_amdgcn_exp2f(fmaf(sT[g * 4 + r], C2, bb));
                t[g * 4 + r] = a; rs += a;
            }
        }
        l_l += rs;

        // ---- pack P (register-resident; slot = key w/ bits2,3 swapped) ----
        u32 pk[8];
#pragma unroll
        for (int i = 0; i < 8; i++) pk[i] = pack_bf16(t[2 * i], t[2 * i + 1]);

        // ---- O^T += V P^T (2 MFMAs of k=16 per d-half) ----
        __builtin_amdgcn_s_setprio(1);
#pragma unroll
        for (int kc = 0; kc < 2; kc++) {
            bf16x8 pf = __builtin_bit_cast(bf16x8,
                make_uint4(pk[4 * kc], pk[4 * kc + 1], pk[4 * kc + 2], pk[4 * kc + 3]));
            bf16x8 va0 = lds_frag(Vl + vfo0[kc]);
            bf16x8 va1 = lds_frag(Vl + vfo1[kc]);
            o0 = __builtin_amdgcn_mfma_f32_32x32x16_bf16(va0, pf, o0, 0, 0, 0);
            o1 = __builtin_amdgcn_mfma_f32_32x32x16_bf16(va1, pf, o1, 0, 0, 0);
        }
        __builtin_amdgcn_s_setprio(0);
        __builtin_amdgcn_s_barrier();          // release buffer cur for re-stage
    }

    // ---- tree combine of 4 key-parity partials (2 barriers) ----
    l_l += __shfl_xor(l_l, 32);
    float* fcb = (float*)SB;                 // 32 KB = 4 segs x 8 KB
    if (p >= 2) {                            // round 1 write: p=2->seg(wq,0), p=3->seg(wq,1)
        float* fc = fcb + (size_t)(wq * 2 + (p & 1)) * 2048;
#pragma unroll
        for (int r = 0; r < 16; r++) fc[r * 64 + lane] = o0[r];
#pragma unroll
        for (int r = 0; r < 16; r++) fc[(16 + r) * 64 + lane] = o1[r];
        lsl[(wq * 2 + (p & 1)) * 64 + lane] = l_l;
    }
    __syncthreads();
    if (p < 2) {                             // round 1 add (parallel on p=0,1)
        float* fc = fcb + (size_t)(wq * 2 + p) * 2048;
#pragma unroll
        for (int r = 0; r < 16; r++) o0[r] += fc[r * 64 + lane];
#pragma unroll
        for (int r = 0; r < 16; r++) o1[r] += fc[(16 + r) * 64 + lane];
        l_l += lsl[(wq * 2 + p) * 64 + lane];
    }
    if (p == 1) {                            // round 2 write (same seg it just read)
        float* fc = fcb + (size_t)(wq * 2 + 1) * 2048;
#pragma unroll
        for (int r = 0; r < 16; r++) fc[r * 64 + lane] = o0[r];
#pragma unroll
        for (int r = 0; r < 16; r++) fc[(16 + r) * 64 + lane] = o1[r];
        lsl[(wq * 2 + 1) * 64 + lane] = l_l;
    }
    __syncthreads();
    if (p == 0) {
        float* fc = fcb + (size_t)(wq * 2 + 1) * 2048;
#pragma unroll
        for (int r = 0; r < 16; r++) o0[r] += fc[r * 64 + lane];
#pragma unroll
        for (int r = 0; r < 16; r++) o1[r] += fc[(16 + r) * 64 + lane];
        l_l += lsl[(wq * 2 + 1) * 64 + lane];
        float inv = 1.0f / l_l;
        const int qg = q0 + wq * 32 + qc;
        u16* Xp = X + (size_t)(b * Sq + qg) * Dm + (bh & 15) * DK;
#pragma unroll
        for (int g = 0; g < 4; g++) {
            *(uint2*)&Xp[8 * g + 4 * half] =
                make_uint2(pack_bf16(o0[g * 4 + 0] * inv, o0[g * 4 + 1] * inv),
                           pack_bf16(o0[g * 4 + 2] * inv, o0[g * 4 + 3] * inv));
            *(uint2*)&Xp[32 + 8 * g + 4 * half] =
                make_uint2(pack_bf16(o1[g * 4 + 0] * inv, o1[g * 4 + 1] * inv),
                           pack_bf16(o1[g * 4 + 2] * inv, o1[g * 4 + 3] * inv));
        }
    }
}

// ---------------------------------------------------------------------------
// Kernel 4: out = X @ Wo + bo (fp32). 128x64 tiles, m-major -> 512 blocks
// (2 blocks/CU; the 128x128 tile would leave 1/CU here).
// ---------------------------------------------------------------------------
__global__ __launch_bounds__(256) void mha_oproj(
    const u16* __restrict__ X, const u16* __restrict__ Wot,
    const float* __restrict__ bo, float* __restrict__ out)
{
    __shared__ __align__(16) u16 As[128 * 64];
    __shared__ __align__(16) u16 Bs[64 * 64];
    const int bx = blockIdx.x;
    const int m0 = (bx & 31) * 128, n0 = (bx >> 5) * 64;
    f32x4 acc[4][2];
    gemm_core_12864(X + (size_t)m0 * Dm, Wot + (size_t)n0 * Dm, As, Bs, acc);
    const int tid = threadIdx.x, lane = tid & 63;
    const int wm = (tid >> 7) & 1, wn = (tid >> 6) & 1;
    const int frow = lane & 15, quad = lane >> 4;
#pragma unroll
    for (int mi = 0; mi < 4; mi++)
#pragma unroll
        for (int ni = 0; ni < 2; ni++)
#pragma unroll
            for (int r = 0; r < 4; r++) {
                int m = m0 + wm * 64 + mi * 16 + quad * 4 + r;
                int n = n0 + wn * 32 + ni * 16 + frow;
                out[(size_t)m * Dm + n] = acc[mi][ni][r] + bo[n];
            }
}

// ---------------------------------------------------------------------------
extern "C" void kernel_launch(void* const* d_in, const int* in_sizes, int n_in,
                              void* d_out, int out_size, void* d_ws, size_t ws_size,
                              hipStream_t stream)
{
    const float* qin  = (const float*)d_in[0];
    const float* kin  = (const float*)d_in[1];
    const float* vin  = (const float*)d_in[2];
    const int*   mask = (const int*)d_in[3];
    const float* Wq   = (const float*)d_in[4];
    const float* bq   = (const float*)d_in[5];
    const float* Wk   = (const float*)d_in[6];
    const float* bk   = (const float*)d_in[7];
    const float* Wv   = (const float*)d_in[8];
    const float* bv   = (const float*)d_in[9];
    const float* Wo   = (const float*)d_in[10];
    const float* bo   = (const float*)d_in[11];
    float* out = (float*)d_out;

    u16* ws = (u16*)d_ws;
    const size_t MW = (size_t)Dm * Dm;
    const size_t MT = (size_t)Bz * Sq * Dm;
    u16* Wqt = ws;
    u16* Wkt = ws + MW;
    u16* Wvt = ws + 2 * MW;
    u16* Wot = ws + 3 * MW;
    u16* Qb  = ws + 4 * MW;
    u16* Kb  = Qb + MT;
    u16* Vb  = Kb + MT;
    u16* Qh  = Vb + MT;
    u16* Kh  = Qh + MT;
    u16* Vt  = Kh + MT;
    float* biasg = (float*)(Vt + MT);          // 16 KB (kept for prep; attn no longer reads)
    int*   compg = (int*)(biasg + Bz * Sq);    // 16 KB (key -> compact pos)
    int*   nkg   = (int*)(compg + Bz * Sq);    // 2 ints (#active keys per b)
    u16* X   = Qb;                             // Qb dead after proj

    hipLaunchKernelGGL(mha_prep, dim3(2048, 1, 4), dim3(256), 0, stream,
                       qin, kin, vin, Wq, Wk, Wv, Wo, mask, Qb, Wqt, biasg, compg, nkg);
    hipLaunchKernelGGL(mha_proj_qkv, dim3(256, 1, 3), dim3(256), 0, stream,
                       Qb, Kb, Vb, Wqt, Wkt, Wvt, bq, bk, bv, compg, Qh, Kh, Vt);
    hipLaunchKernelGGL(mha_attn, dim3(32, 32), dim3(512), 0, stream,
                       Qh, Kh, Vt, nkg, X);
    hipLaunchKernelGGL(mha_oproj, dim3(512), dim3(256), 0, stream,
                       X, Wot, bo, out);
}

// Round 9
// 211.025 us; speedup vs baseline: 1.3064x; 1.0306x over previous
//
#include <hip/hip_runtime.h>
#include <hip/hip_bf16.h>

typedef unsigned short u16;
typedef unsigned int u32;
typedef __attribute__((ext_vector_type(8))) __bf16 bf16x8;
typedef __attribute__((ext_vector_type(4))) float f32x4;
typedef __attribute__((ext_vector_type(16))) float f32x16;

constexpr int Bz = 2, Sq = 2048, Dm = 1024, Hn = 16, DK = 64;

__device__ __forceinline__ u16 f2bf(float f) {
    u32 u = __builtin_bit_cast(u32, f);
    return (u16)((u + 0x7FFFu + ((u >> 16) & 1u)) >> 16);   // RNE
}

__device__ __forceinline__ u32 pack_bf16(float a, float b) {
#if __has_builtin(__builtin_amdgcn_cvt_pk_bf16_f32)
    return __builtin_bit_cast(u32, __builtin_amdgcn_cvt_pk_bf16_f32(a, b));
#else
    return (u32)f2bf(a) | ((u32)f2bf(b) << 16);
#endif
}

__device__ __forceinline__ bf16x8 lds_frag(const u16* p) {
    return __builtin_bit_cast(bf16x8, *(const uint4*)p);
}
__device__ __forceinline__ bf16x8 gfrag(const u16* p) {
    return __builtin_bit_cast(bf16x8, *(const uint4*)p);
}
__device__ __forceinline__ int swz(int r) { return (r ^ (r >> 3)) & 7; }

// async global->LDS, 16B per lane; dest = wave-uniform base + lane*16
__device__ __forceinline__ void gll16(const u16* g, u16* l) {
    __builtin_amdgcn_global_load_lds(
        (const __attribute__((address_space(1))) void*)g,
        (__attribute__((address_space(3))) void*)l, 16, 0, 0);
}

// ---------------------------------------------------------------------------
// Kernel 1 (fused prep): z<3: cast q/k/v fp32->bf16. z==3:
//   bx<1024     : transpose+cast the 4 weights (64x64 tiles) -> Wt [N,K] bf16
//   bx==1024/5  : per-batch key compaction scan: invcomp[pos] = token index
//                 (total permutation: actives mask==0 first, masked tail),
//                 nk[b] = #active. Bias is COMPUTED in attn (key<nk ? 0:-inf)
//                 so no bias array is needed.
// ---------------------------------------------------------------------------
__global__ __launch_bounds__(256) void mha_prep(
    const float* __restrict__ q, const float* __restrict__ k,
    const float* __restrict__ v,
    const float* __restrict__ w0, const float* __restrict__ w1,
    const float* __restrict__ w2, const float* __restrict__ w3,
    const int* __restrict__ mask,
    u16* __restrict__ qkv_dst, u16* __restrict__ wt_dst,
    int* __restrict__ invcg, int* __restrict__ nkg)
{
    __shared__ float tl[64 * 65];
    __shared__ int sc[256];
    const int z = blockIdx.z, tid = threadIdx.x;
    if (z < 3) {
        const float* s = (z == 0) ? q : (z == 1) ? k : v;
        u16* d = qkv_dst + (size_t)z * 4 * 1024 * 1024;
        size_t i = ((size_t)blockIdx.x * 256 + tid) * 8;
        float4 a = *(const float4*)(s + i);
        float4 b = *(const float4*)(s + i + 4);
        *(uint4*)(d + i) = make_uint4(pack_bf16(a.x, a.y), pack_bf16(a.z, a.w),
                                      pack_bf16(b.x, b.y), pack_bf16(b.z, b.w));
        return;
    }
    const int bx = blockIdx.x;
    if (bx >= 1026) return;
    if (bx >= 1024) {   // compaction scan for batch b
        const int b = bx - 1024;
        const int* mp = mask + b * Sq;
        int4 m0_ = ((const int4*)mp)[tid * 2];
        int4 m1_ = ((const int4*)mp)[tid * 2 + 1];
        int a[8];
        a[0] = (m0_.x == 0); a[1] = (m0_.y == 0); a[2] = (m0_.z == 0); a[3] = (m0_.w == 0);
        a[4] = (m1_.x == 0); a[5] = (m1_.y == 0); a[6] = (m1_.z == 0); a[7] = (m1_.w == 0);
        int cnt = 0;
#pragma unroll
        for (int j = 0; j < 8; j++) cnt += a[j];
        sc[tid] = cnt;
        __syncthreads();
        for (int off = 1; off < 256; off <<= 1) {
            int u = (tid >= off) ? sc[tid - off] : 0;
            int vv = sc[tid];
            __syncthreads();
            sc[tid] = vv + u;
            __syncthreads();
        }
        const int incl = sc[tid];
        const int nk = sc[255];
        int pa = incl - cnt;            // actives before my 8 elems
        int pi = nk + tid * 8 - pa;     // nk + inactives before
        int* icp = invcg + b * Sq;
#pragma unroll
        for (int j = 0; j < 8; j++) {
            int pos = a[j] ? pa++ : pi++;
            icp[pos] = tid * 8 + j;     // invcomp: compact pos -> token
        }
        if (tid == 0) nkg[b] = nk;
        return;
    }
    // weight transpose: matrix zi, 64x64 tile (tr,tc)
    const int zi = bx >> 8, t = bx & 255, tr = t >> 4, tc = t & 15;
    const float* src = (zi == 0) ? w0 : (zi == 1) ? w1 : (zi == 2) ? w2 : w3;
    u16* d = wt_dst + (size_t)zi * Dm * Dm;
    {
        int r = tid >> 2, cq = (tid & 3) * 16;
        const float* sp = src + (size_t)(tr * 64 + r) * Dm + tc * 64 + cq;
#pragma unroll
        for (int j = 0; j < 4; j++) {
            float4 vv = *(const float4*)(sp + j * 4);
            tl[r * 65 + cq + j * 4 + 0] = vv.x;
            tl[r * 65 + cq + j * 4 + 1] = vv.y;
            tl[r * 65 + cq + j * 4 + 2] = vv.z;
            tl[r * 65 + cq + j * 4 + 3] = vv.w;
        }
    }
    __syncthreads();
    {
        int rr = tid >> 2, cc = (tid & 3) * 16;
        u16* dp = d + (size_t)(tc * 64 + rr) * Dm + tr * 64 + cc;
        u32 px[8];
#pragma unroll
        for (int j = 0; j < 8; j++)
            px[j] = pack_bf16(tl[(cc + 2 * j) * 65 + rr], tl[(cc + 2 * j + 1) * 65 + rr]);
        *(uint4*)dp       = make_uint4(px[0], px[1], px[2], px[3]);
        *(uint4*)(dp + 8) = make_uint4(px[4], px[5], px[6], px[7]);
    }
}

// ---------------------------------------------------------------------------
// GEMM core A (m97 structure): C[128 x 128] = A[rows x K] @ B[rows x K]^T,
// K=1024, BK=64. 256 thr = 4 waves (2m x 2n), wave tile 64x64, acc[4][4].
// LDS 32 KB. global_load_lds staging, XOR-swizzled tiles. Source rows are
// taken from per-thread arrays arow/brow (absolute rows) so callers can
// GATHER token rows through the compaction permutation; the swizzle stays
// keyed to the LDS-relative row r (destination layout).
// ---------------------------------------------------------------------------
__device__ __forceinline__ void gemm_core_128128(
    const u16* __restrict__ Ab, const u16* __restrict__ Bb,
    const int (&arow)[4], const int (&brow)[4],
    u16* As, u16* Bs, f32x4 (&acc)[4][4])
{
    const int tid = threadIdx.x, lane = tid & 63;
    const int wm = (tid >> 7) & 1, wn = (tid >> 6) & 1;
    const int frow = lane & 15, quad = lane >> 4;

#pragma unroll
    for (int mi = 0; mi < 4; mi++)
#pragma unroll
        for (int ni = 0; ni < 4; ni++) acc[mi][ni] = (f32x4){0.f, 0.f, 0.f, 0.f};

    for (int k0 = 0; k0 < 1024; k0 += 64) {
#pragma unroll
        for (int i = 0; i < 4; i++) {
            int id = tid + i * 256, r = id >> 3, c = id & 7;
            gll16(Ab + (size_t)arow[i] * 1024 + k0 + (c ^ swz(r)) * 8, As + (size_t)id * 8);
        }
#pragma unroll
        for (int i = 0; i < 4; i++) {
            int id = tid + i * 256, r = id >> 3, c = id & 7;
            gll16(Bb + (size_t)brow[i] * 1024 + k0 + (c ^ swz(r)) * 8, Bs + (size_t)id * 8);
        }
        __syncthreads();
#pragma unroll
        for (int ks = 0; ks < 2; ks++) {
            bf16x8 af[4], bfr[4];
#pragma unroll
            for (int mi = 0; mi < 4; mi++) {
                int r = wm * 64 + mi * 16 + frow;
                af[mi] = lds_frag(As + r * 64 + ((ks * 4 + quad) ^ swz(r)) * 8);
            }
#pragma unroll
            for (int ni = 0; ni < 4; ni++) {
                int r = wn * 64 + ni * 16 + frow;
                bfr[ni] = lds_frag(Bs + r * 64 + ((ks * 4 + quad) ^ swz(r)) * 8);
            }
#pragma unroll
            for (int mi = 0; mi < 4; mi++)
#pragma unroll
                for (int ni = 0; ni < 4; ni++)
                    acc[mi][ni] = __builtin_amdgcn_mfma_f32_16x16x32_bf16(
                        af[mi], bfr[ni], acc[mi][ni], 0, 0, 0);
        }
        __syncthreads();
    }
}

// ---------------------------------------------------------------------------
// GEMM core B (small tile, for oproj where N=1024 would give 1 block/CU
// with the 128x128 tile): C[128 x 64] = A[128xK] @ B[64 x K]^T.
// ---------------------------------------------------------------------------
__device__ __forceinline__ void gemm_core_12864(
    const u16* __restrict__ Ab, const u16* __restrict__ Bb,
    u16* As, u16* Bs, f32x4 (&acc)[4][2])
{
    const int tid = threadIdx.x, lane = tid & 63;
    const int wm = (tid >> 7) & 1, wn = (tid >> 6) & 1;
    const int frow = lane & 15, quad = lane >> 4;

#pragma unroll
    for (int mi = 0; mi < 4; mi++)
#pragma unroll
        for (int ni = 0; ni < 2; ni++) acc[mi][ni] = (f32x4){0.f, 0.f, 0.f, 0.f};

    for (int k0 = 0; k0 < 1024; k0 += 64) {
#pragma unroll
        for (int i = 0; i < 4; i++) {
            int id = tid + i * 256, r = id >> 3, c = id & 7;
            gll16(Ab + (size_t)r * 1024 + k0 + (c ^ swz(r)) * 8, As + (size_t)id * 8);
        }
#pragma unroll
        for (int i = 0; i < 2; i++) {
            int id = tid + i * 256, r = id >> 3, c = id & 7;
            gll16(Bb + (size_t)r * 1024 + k0 + (c ^ swz(r)) * 8, Bs + (size_t)id * 8);
        }
        __syncthreads();
#pragma unroll
        for (int ks = 0; ks < 2; ks++) {
            bf16x8 af[4], bfr[2];
#pragma unroll
            for (int mi = 0; mi < 4; mi++) {
                int r = wm * 64 + mi * 16 + frow;
                af[mi] = lds_frag(As + r * 64 + ((ks * 4 + quad) ^ swz(r)) * 8);
            }
#pragma unroll
            for (int ni = 0; ni < 2; ni++) {
                int r = wn * 32 + ni * 16 + frow;
                bfr[ni] = lds_frag(Bs + r * 64 + ((ks * 4 + quad) ^ swz(r)) * 8);
            }
#pragma unroll
            for (int mi = 0; mi < 4; mi++)
#pragma unroll
                for (int ni = 0; ni < 2; ni++)
                    acc[mi][ni] = __builtin_amdgcn_mfma_f32_16x16x32_bf16(
                        af[mi], bfr[ni], acc[mi][ni], 0, 0, 0);
        }
        __syncthreads();
    }
}

// ---------------------------------------------------------------------------
// Kernel 2: QKV projections, 128x128 tiles, 256 blocks per z.
// COMPACTION-AWARE WORK SKIP: attn only reads compacted key positions
// < nkp = ceil128(nk), so:
//   z=0: Q (full) -> [B,H,S,DK].
//   z=1: K gathers A-rows via invcomp (output row = compact pos directly);
//        m-tiles with pos0 >= nkp(b) early-exit (~half the work).
//   z=2: V gathers B-rows via invcomp -> V'^T [B,H,DK,bitswap(pos)];
//        n-tiles with pos0 >= nkp(b) early-exit.
// Pad rows [nk, nkp) get projections of real masked tokens (finite junk;
// attn's computed bias zeroes their weight). nkp is 128-aligned so no
// partial tiles exist. Epilogues no longer need comp[] indirection.
// ---------------------------------------------------------------------------
__global__ __launch_bounds__(256, 3) void mha_proj_qkv(
    const u16* __restrict__ Qb, const u16* __restrict__ Kb, const u16* __restrict__ Vb,
    const u16* __restrict__ Wqt, const u16* __restrict__ Wkt, const u16* __restrict__ Wvt,
    const float* __restrict__ bq, const float* __restrict__ bk, const float* __restrict__ bv,
    const int* __restrict__ invc, const int* __restrict__ nkg,
    u16* __restrict__ Qh, u16* __restrict__ Kh, u16* __restrict__ Vt)
{
    __shared__ __align__(16) u16 As[128 * 64];
    __shared__ __align__(16) u16 Bs[128 * 64];
    const int z = blockIdx.z, bx = blockIdx.x;
    const int tid = threadIdx.x;
    const u16* Ab; const u16* Bb; const float* bias;
    int m0, n0;
    if (z < 2) {
        m0 = (bx & 31) * 128;        // 32 m-tiles minor: XCD = m_t%8, tokens clustered
        n0 = (bx >> 5) * 128;        // 8 n-tiles
        Ab = (z == 0) ? Qb : Kb;
        Bb = (z == 0) ? Wqt : Wkt;
        bias = (z == 0) ? bq : bk;
    } else {
        m0 = (bx >> 5) * 128;        // 8 m-tiles (outdim)
        n0 = (bx & 31) * 128;        // 32 n-tiles minor: XCD = n_t%8, Vb tokens clustered
        Ab = Wvt;
        Bb = Vb;
        bias = bv;
    }

    int arow[4], brow[4];
#pragma unroll
    for (int i = 0; i < 4; i++) {
        int r = (tid + i * 256) >> 3;
        arow[i] = m0 + r;
        brow[i] = n0 + r;
    }
    if (z == 1) {                    // gather K token rows through invcomp
        const int bb = m0 >> 11, pos0 = m0 & 2047;
        const int nkp = (nkg[bb] + 127) & ~127;
        if (pos0 >= nkp) return;     // block-uniform early exit
        const int* ic = invc + ((size_t)bb << 11) + pos0;
#pragma unroll
        for (int i = 0; i < 4; i++) {
            int r = (tid + i * 256) >> 3;
            arow[i] = (bb << 11) + ic[r];
        }
    } else if (z == 2) {             // gather V token rows through invcomp
        const int bj = n0 >> 11, pos0 = n0 & 2047;
        const int nkp = (nkg[bj] + 127) & ~127;
        if (pos0 >= nkp) return;
        const int* ic = invc + ((size_t)bj << 11) + pos0;
#pragma unroll
        for (int i = 0; i < 4; i++) {
            int r = (tid + i * 256) >> 3;
            brow[i] = (bj << 11) + ic[r];
        }
    }

    f32x4 acc[4][4];
    gemm_core_128128(Ab, Bb, arow, brow, As, Bs, acc);

    const int lane = tid & 63;
    const int wm = (tid >> 7) & 1, wn = (tid >> 6) & 1;
    const int frow = lane & 15, quad = lane >> 4;
    u16* dstq = (z == 0) ? Qh : Kh;
#pragma unroll
    for (int mi = 0; mi < 4; mi++)
#pragma unroll
        for (int ni = 0; ni < 4; ni++)
#pragma unroll
            for (int r = 0; r < 4; r++) {
                int i = m0 + wm * 64 + mi * 16 + quad * 4 + r;
                int j = n0 + wn * 64 + ni * 16 + frow;
                if (z < 2) {
                    float val = acc[mi][ni][r] + bias[j];
                    int b = i >> 11, s = i & (Sq - 1);   // z=1: s IS compact pos
                    int h = j >> 6, dk = j & (DK - 1);
                    dstq[((size_t)(b * Hn + h) * Sq + s) * DK + dk] = f2bf(val);
                } else {
                    float val = acc[mi][ni][r] + bias[i];
                    int h = i >> 6, dk = i & (DK - 1);
                    int bj = j >> 11, cs = j & (Sq - 1); // compact pos
                    int sp = (cs & ~12) | ((cs & 4) << 1) | ((cs & 8) >> 1);  // swap bits 2,3
                    Vt[((size_t)(bj * Hn + h) * DK + dk) * Sq + sp] = f2bf(val);
                }
            }
}

// ---------------------------------------------------------------------------
// Kernel 3: flash attention over COMPACTED keys. Inner math = frozen R4
// body (the only spill-free compaction-aware variant). R8-verified:
// VGPR 52, WRITE_SIZE 8192 KB (no spill), 45.4 us.
//  (1) bias COMPUTED not loaded: bias = (key<nk ? 0:-inf). No VMEM in the
//      compute phase, so vmcnt tracks only staging loads.
//  (2) double-buffered staging with counted waits: stage tile t+1, then
//      s_waitcnt vmcnt(4), sched_barrier(0), raw s_barrier; trailing raw
//      s_barrier protects re-staging. Last iter vmcnt(0).
// SPILL GUARD: WRITE_SIZE must stay 8192 KB. __launch_bounds__(512,4);
// DO NOT raise the min-waves arg ((512,8) spilled catastrophically, R3).
// ---------------------------------------------------------------------------
__global__ __launch_bounds__(512, 4) void mha_attn(
    const u16* __restrict__ Qh, const u16* __restrict__ Kh, const u16* __restrict__ Vt,
    const int* __restrict__ nkg, u16* __restrict__ X)
{
    const int bh = blockIdx.x;                 // b*16+h -> XCD = bh%8
    const int b = bh >> 4;
    const int q0 = blockIdx.y * 64;
    const int tid = threadIdx.x, lane = tid & 63, w = tid >> 6;
    const int wq = w & 1, p = w >> 1;          // q-group, key-parity 0..3
    const int qc = lane & 31, half = lane >> 5;
    constexpr float C2 = 0.125f * 1.44269504f; // 1/sqrt(DK) * log2(e)

    // 2 buffers x (K tile 16 KB | V tile 16 KB); aliased as 32 KB combine
    // scratch after the k-loop. Per-buffer layout: [Ks 8192 u16][Vs 8192 u16].
    __shared__ __align__(16) u16 SB[2 * 16384];
    __shared__ float lsl[256];

    const u16* Qp = Qh + (size_t)bh * Sq * DK;
    const u16* Kp = Kh + (size_t)bh * Sq * DK;
    const u16* Vp = Vt + (size_t)bh * DK * Sq;
    const int nk = nkg[b];
    const int nt = (nk + 127) >> 7;            // tiles of 128 compacted keys

    // Q B-frags direct from global (once): lane n=qc; k = kc*16 + half*8 + j
    bf16x8 qf[4];
    {
        const u16* qrow = Qp + (size_t)(q0 + wq * 32 + qc) * DK + half * 8;
#pragma unroll
        for (int kc = 0; kc < 4; kc++) qf[kc] = gfrag(qrow + kc * 16);
    }

    // staging precompute: 4 gll16 per tile (2 K + 2 V), 32 KB/tile
    const int idA = tid, idB = tid + 512;
    const u16* ksA = Kp + (size_t)(idA >> 3) * DK + ((idA & 7) ^ swz(idA >> 3)) * 8;
    const u16* ksB = Kp + (size_t)(idB >> 3) * DK + ((idB & 7) ^ swz(idB >> 3)) * 8;
    const u16* vsA = Vp + (size_t)(idA >> 4) * Sq + (((idA & 15) ^ ((idA >> 4) & 15)) * 8);
    const u16* vsB = Vp + (size_t)(idB >> 4) * Sq + (((idB & 15) ^ ((idB >> 4) & 15)) * 8);
    u16* kdA = SB + idA * 8;
    u16* kdB = SB + idB * 8;
    u16* vdA = SB + 8192 + idA * 8;
    u16* vdB = SB + 8192 + idB * 8;

    auto stage = [&](int cur, int kb) {
        const int co = cur * 16384;
        gll16(ksA + (size_t)kb * DK, kdA + co);
        gll16(ksB + (size_t)kb * DK, kdB + co);
        gll16(vsA + kb, vdA + co);
        gll16(vsB + kb, vdB + co);
    };

    // fragment LDS offsets (loop-invariant, relative to buffer base)
    const int kr = p * 32 + qc;
    int kfo[4];
#pragma unroll
    for (int kc = 0; kc < 4; kc++)
        kfo[kc] = kr * 64 + (((kc * 2 + half) ^ swz(kr)) * 8);
    int vfo0[2], vfo1[2];
#pragma unroll
    for (int kc = 0; kc < 2; kc++) {
        int ch = p * 4 + kc * 2 + half;
        vfo0[kc] = qc * 128 + ((ch ^ (qc & 15)) * 8);
        vfo1[kc] = (32 + qc) * 128 + ((ch ^ (qc & 15)) * 8);
    }
    const int kbias = p * 32 + 4 * half;       // + kb + 8g + r = key index

    float l_l = 0.f;
    f32x16 o0, o1;
#pragma unroll
    for (int i = 0; i < 16; i++) { o0[i] = 0.f; o1[i] = 0.f; }

    stage(0, 0);
    for (int it = 0; it < nt; it++) {
        const int cur = it & 1;
        if (it + 1 < nt) {
            stage(cur ^ 1, (it + 1) * 128);
            asm volatile("s_waitcnt vmcnt(4)" ::: "memory");  // tile t done, t+1 in flight
        } else {
            asm volatile("s_waitcnt vmcnt(0)" ::: "memory");
        }
        __builtin_amdgcn_sched_barrier(0);
        __builtin_amdgcn_s_barrier();

        const u16* Kl = SB + cur * 16384;
        const u16* Vl = Kl + 8192;

        // ---- S^T = K Q^T on this wave's 32-key slice ----
        f32x16 sT;
#pragma unroll
        for (int i = 0; i < 16; i++) sT[i] = 0.f;
        __builtin_amdgcn_s_setprio(1);
#pragma unroll
        for (int kc = 0; kc < 4; kc++) {
            bf16x8 ka = lds_frag(Kl + kfo[kc]);
            sT = __builtin_amdgcn_mfma_f32_32x32x16_bf16(ka, qf[kc], sT, 0, 0, 0);
        }
        __builtin_amdgcn_s_setprio(0);

        // ---- no-max exp2 softmax; bias computed: key<nk ? 0 : -inf ----
        const int thr = nk - it * 128 - kbias; // key<nk  <=>  8g+r < thr
        float t[16], rs = 0.f;
#pragma unroll
        for (int g = 0; g < 4; g++) {
#pragma unroll
            for (int r = 0; r < 4; r++) {
                float bb = (8 * g + r < thr) ? 0.f : -1.44269504e10f;
                float a = __builtin_amdgcn_exp2f(fmaf(sT[g * 4 + r], C2, bb));
                t[g * 4 + r] = a; rs += a;
            }
        }
        l_l += rs;

        // ---- pack P (register-resident; slot = key w/ bits2,3 swapped) ----
        u32 pk[8];
#pragma unroll
        for (int i = 0; i < 8; i++) pk[i] = pack_bf16(t[2 * i], t[2 * i + 1]);

        // ---- O^T += V P^T (2 MFMAs of k=16 per d-half) ----
        __builtin_amdgcn_s_setprio(1);
#pragma unroll
        for (int kc = 0; kc < 2; kc++) {
            bf16x8 pf = __builtin_bit_cast(bf16x8,
                make_uint4(pk[4 * kc], pk[4 * kc + 1], pk[4 * kc + 2], pk[4 * kc + 3]));
            bf16x8 va0 = lds_frag(Vl + vfo0[kc]);
            bf16x8 va1 = lds_frag(Vl + vfo1[kc]);
            o0 = __builtin_amdgcn_mfma_f32_32x32x16_bf16(va0, pf, o0, 0, 0, 0);
            o1 = __builtin_amdgcn_mfma_f32_32x32x16_bf16(va1, pf, o1, 0, 0, 0);
        }
        __builtin_amdgcn_s_setprio(0);
        __builtin_amdgcn_s_barrier();          // release buffer cur for re-stage
    }

    // ---- tree combine of 4 key-parity partials (2 barriers) ----
    l_l += __shfl_xor(l_l, 32);
    float* fcb = (float*)SB;                 // 32 KB = 4 segs x 8 KB
    if (p >= 2) {                            // round 1 write: p=2->seg(wq,0), p=3->seg(wq,1)
        float* fc = fcb + (size_t)(wq * 2 + (p & 1)) * 2048;
#pragma unroll
        for (int r = 0; r < 16; r++) fc[r * 64 + lane] = o0[r];
#pragma unroll
        for (int r = 0; r < 16; r++) fc[(16 + r) * 64 + lane] = o1[r];
        lsl[(wq * 2 + (p & 1)) * 64 + lane] = l_l;
    }
    __syncthreads();
    if (p < 2) {                             // round 1 add (parallel on p=0,1)
        float* fc = fcb + (size_t)(wq * 2 + p) * 2048;
#pragma unroll
        for (int r = 0; r < 16; r++) o0[r] += fc[r * 64 + lane];
#pragma unroll
        for (int r = 0; r < 16; r++) o1[r] += fc[(16 + r) * 64 + lane];
        l_l += lsl[(wq * 2 + p) * 64 + lane];
    }
    if (p == 1) {                            // round 2 write (same seg it just read)
        float* fc = fcb + (size_t)(wq * 2 + 1) * 2048;
#pragma unroll
        for (int r = 0; r < 16; r++) fc[r * 64 + lane] = o0[r];
#pragma unroll
        for (int r = 0; r < 16; r++) fc[(16 + r) * 64 + lane] = o1[r];
        lsl[(wq * 2 + 1) * 64 + lane] = l_l;
    }
    __syncthreads();
    if (p == 0) {
        float* fc = fcb + (size_t)(wq * 2 + 1) * 2048;
#pragma unroll
        for (int r = 0; r < 16; r++) o0[r] += fc[r * 64 + lane];
#pragma unroll
        for (int r = 0; r < 16; r++) o1[r] += fc[(16 + r) * 64 + lane];
        l_l += lsl[(wq * 2 + 1) * 64 + lane];
        float inv = 1.0f / l_l;
        const int qg = q0 + wq * 32 + qc;
        u16* Xp = X + (size_t)(b * Sq + qg) * Dm + (bh & 15) * DK;
#pragma unroll
        for (int g = 0; g < 4; g++) {
            *(uint2*)&Xp[8 * g + 4 * half] =
                make_uint2(pack_bf16(o0[g * 4 + 0] * inv, o0[g * 4 + 1] * inv),
                           pack_bf16(o0[g * 4 + 2] * inv, o0[g * 4 + 3] * inv));
            *(uint2*)&Xp[32 + 8 * g + 4 * half] =
                make_uint2(pack_bf16(o1[g * 4 + 0] * inv, o1[g * 4 + 1] * inv),
                           pack_bf16(o1[g * 4 + 2] * inv, o1[g * 4 + 3] * inv));
        }
    }
}

// ---------------------------------------------------------------------------
// Kernel 4: out = X @ Wo + bo (fp32). 128x64 tiles, m-major -> 512 blocks
// (2 blocks/CU; the 128x128 tile would leave 1/CU here).
// ---------------------------------------------------------------------------
__global__ __launch_bounds__(256) void mha_oproj(
    const u16* __restrict__ X, const u16* __restrict__ Wot,
    const float* __restrict__ bo, float* __restrict__ out)
{
    __shared__ __align__(16) u16 As[128 * 64];
    __shared__ __align__(16) u16 Bs[64 * 64];
    const int bx = blockIdx.x;
    const int m0 = (bx & 31) * 128, n0 = (bx >> 5) * 64;
    f32x4 acc[4][2];
    gemm_core_12864(X + (size_t)m0 * Dm, Wot + (size_t)n0 * Dm, As, Bs, acc);
    const int tid = threadIdx.x, lane = tid & 63;
    const int wm = (tid >> 7) & 1, wn = (tid >> 6) & 1;
    const int frow = lane & 15, quad = lane >> 4;
#pragma unroll
    for (int mi = 0; mi < 4; mi++)
#pragma unroll
        for (int ni = 0; ni < 2; ni++)
#pragma unroll
            for (int r = 0; r < 4; r++) {
                int m = m0 + wm * 64 + mi * 16 + quad * 4 + r;
                int n = n0 + wn * 32 + ni * 16 + frow;
                out[(size_t)m * Dm + n] = acc[mi][ni][r] + bo[n];
            }
}

// ---------------------------------------------------------------------------
extern "C" void kernel_launch(void* const* d_in, const int* in_sizes, int n_in,
                              void* d_out, int out_size, void* d_ws, size_t ws_size,
                              hipStream_t stream)
{
    const float* qin  = (const float*)d_in[0];
    const float* kin  = (const float*)d_in[1];
    const float* vin  = (const float*)d_in[2];
    const int*   mask = (const int*)d_in[3];
    const float* Wq   = (const float*)d_in[4];
    const float* bq   = (const float*)d_in[5];
    const float* Wk   = (const float*)d_in[6];
    const float* bk   = (const float*)d_in[7];
    const float* Wv   = (const float*)d_in[8];
    const float* bv   = (const float*)d_in[9];
    const float* Wo   = (const float*)d_in[10];
    const float* bo   = (const float*)d_in[11];
    float* out = (float*)d_out;

    u16* ws = (u16*)d_ws;
    const size_t MW = (size_t)Dm * Dm;
    const size_t MT = (size_t)Bz * Sq * Dm;
    u16* Wqt = ws;
    u16* Wkt = ws + MW;
    u16* Wvt = ws + 2 * MW;
    u16* Wot = ws + 3 * MW;
    u16* Qb  = ws + 4 * MW;
    u16* Kb  = Qb + MT;
    u16* Vb  = Kb + MT;
    u16* Qh  = Vb + MT;
    u16* Kh  = Qh + MT;
    u16* Vt  = Kh + MT;
    int*   invcg = (int*)(Vt + MT);            // 16 KB (compact pos -> token)
    int*   nkg   = invcg + Bz * Sq;            // 2 ints (#active keys per b)
    u16* X   = Qb;                             // Qb dead after proj

    hipLaunchKernelGGL(mha_prep, dim3(2048, 1, 4), dim3(256), 0, stream,
                       qin, kin, vin, Wq, Wk, Wv, Wo, mask, Qb, Wqt, invcg, nkg);
    hipLaunchKernelGGL(mha_proj_qkv, dim3(256, 1, 3), dim3(256), 0, stream,
                       Qb, Kb, Vb, Wqt, Wkt, Wvt, bq, bk, bv, invcg, nkg, Qh, Kh, Vt);
    hipLaunchKernelGGL(mha_attn, dim3(32, 32), dim3(512), 0, stream,
                       Qh, Kh, Vt, nkg, X);
    hipLaunchKernelGGL(mha_oproj, dim3(512), dim3(256), 0, stream,
                       X, Wot, bo, out);
}

// Round 10
// 209.136 us; speedup vs baseline: 1.3182x; 1.0090x over previous
//
#include <hip/hip_runtime.h>
#include <hip/hip_bf16.h>

typedef unsigned short u16;
typedef unsigned int u32;
typedef __attribute__((ext_vector_type(8))) __bf16 bf16x8;
typedef __attribute__((ext_vector_type(4))) float f32x4;
typedef __attribute__((ext_vector_type(16))) float f32x16;

constexpr int Bz = 2, Sq = 2048, Dm = 1024, Hn = 16, DK = 64;

__device__ __forceinline__ u16 f2bf(float f) {
    u32 u = __builtin_bit_cast(u32, f);
    return (u16)((u + 0x7FFFu + ((u >> 16) & 1u)) >> 16);   // RNE
}

__device__ __forceinline__ u32 pack_bf16(float a, float b) {
#if __has_builtin(__builtin_amdgcn_cvt_pk_bf16_f32)
    return __builtin_bit_cast(u32, __builtin_amdgcn_cvt_pk_bf16_f32(a, b));
#else
    return (u32)f2bf(a) | ((u32)f2bf(b) << 16);
#endif
}

__device__ __forceinline__ bf16x8 lds_frag(const u16* p) {
    return __builtin_bit_cast(bf16x8, *(const uint4*)p);
}
__device__ __forceinline__ bf16x8 gfrag(const u16* p) {
    return __builtin_bit_cast(bf16x8, *(const uint4*)p);
}
__device__ __forceinline__ int swz(int r) { return (r ^ (r >> 3)) & 7; }

// async global->LDS, 16B per lane; dest = wave-uniform base + lane*16
__device__ __forceinline__ void gll16(const u16* g, u16* l) {
    __builtin_amdgcn_global_load_lds(
        (const __attribute__((address_space(1))) void*)g,
        (__attribute__((address_space(3))) void*)l, 16, 0, 0);
}

// ---------------------------------------------------------------------------
// Kernel 1 (fused prep): z<3: cast q/k/v fp32->bf16. z==3:
//   bx<1024     : transpose+cast the 4 weights (64x64 tiles) -> Wt [N,K] bf16
//   bx==1024/5  : per-batch key compaction scan: invcomp[pos] = token index
//                 (total permutation: actives mask==0 first, masked tail),
//                 nk[b] = #active. Bias is COMPUTED in attn (key<nk ? 0:-inf)
//                 so no bias array is needed.
// ---------------------------------------------------------------------------
__global__ __launch_bounds__(256) void mha_prep(
    const float* __restrict__ q, const float* __restrict__ k,
    const float* __restrict__ v,
    const float* __restrict__ w0, const float* __restrict__ w1,
    const float* __restrict__ w2, const float* __restrict__ w3,
    const int* __restrict__ mask,
    u16* __restrict__ qkv_dst, u16* __restrict__ wt_dst,
    int* __restrict__ invcg, int* __restrict__ nkg)
{
    __shared__ float tl[64 * 65];
    __shared__ int sc[256];
    const int z = blockIdx.z, tid = threadIdx.x;
    if (z < 3) {
        const float* s = (z == 0) ? q : (z == 1) ? k : v;
        u16* d = qkv_dst + (size_t)z * 4 * 1024 * 1024;
        size_t i = ((size_t)blockIdx.x * 256 + tid) * 8;
        float4 a = *(const float4*)(s + i);
        float4 b = *(const float4*)(s + i + 4);
        *(uint4*)(d + i) = make_uint4(pack_bf16(a.x, a.y), pack_bf16(a.z, a.w),
                                      pack_bf16(b.x, b.y), pack_bf16(b.z, b.w));
        return;
    }
    const int bx = blockIdx.x;
    if (bx >= 1026) return;
    if (bx >= 1024) {   // compaction scan for batch b
        const int b = bx - 1024;
        const int* mp = mask + b * Sq;
        int4 m0_ = ((const int4*)mp)[tid * 2];
        int4 m1_ = ((const int4*)mp)[tid * 2 + 1];
        int a[8];
        a[0] = (m0_.x == 0); a[1] = (m0_.y == 0); a[2] = (m0_.z == 0); a[3] = (m0_.w == 0);
        a[4] = (m1_.x == 0); a[5] = (m1_.y == 0); a[6] = (m1_.z == 0); a[7] = (m1_.w == 0);
        int cnt = 0;
#pragma unroll
        for (int j = 0; j < 8; j++) cnt += a[j];
        sc[tid] = cnt;
        __syncthreads();
        for (int off = 1; off < 256; off <<= 1) {
            int u = (tid >= off) ? sc[tid - off] : 0;
            int vv = sc[tid];
            __syncthreads();
            sc[tid] = vv + u;
            __syncthreads();
        }
        const int incl = sc[tid];
        const int nk = sc[255];
        int pa = incl - cnt;            // actives before my 8 elems
        int pi = nk + tid * 8 - pa;     // nk + inactives before
        int* icp = invcg + b * Sq;
#pragma unroll
        for (int j = 0; j < 8; j++) {
            int pos = a[j] ? pa++ : pi++;
            icp[pos] = tid * 8 + j;     // invcomp: compact pos -> token
        }
        if (tid == 0) nkg[b] = nk;
        return;
    }
    // weight transpose: matrix zi, 64x64 tile (tr,tc)
    const int zi = bx >> 8, t = bx & 255, tr = t >> 4, tc = t & 15;
    const float* src = (zi == 0) ? w0 : (zi == 1) ? w1 : (zi == 2) ? w2 : w3;
    u16* d = wt_dst + (size_t)zi * Dm * Dm;
    {
        int r = tid >> 2, cq = (tid & 3) * 16;
        const float* sp = src + (size_t)(tr * 64 + r) * Dm + tc * 64 + cq;
#pragma unroll
        for (int j = 0; j < 4; j++) {
            float4 vv = *(const float4*)(sp + j * 4);
            tl[r * 65 + cq + j * 4 + 0] = vv.x;
            tl[r * 65 + cq + j * 4 + 1] = vv.y;
            tl[r * 65 + cq + j * 4 + 2] = vv.z;
            tl[r * 65 + cq + j * 4 + 3] = vv.w;
        }
    }
    __syncthreads();
    {
        int rr = tid >> 2, cc = (tid & 3) * 16;
        u16* dp = d + (size_t)(tc * 64 + rr) * Dm + tr * 64 + cc;
        u32 px[8];
#pragma unroll
        for (int j = 0; j < 8; j++)
            px[j] = pack_bf16(tl[(cc + 2 * j) * 65 + rr], tl[(cc + 2 * j + 1) * 65 + rr]);
        *(uint4*)dp       = make_uint4(px[0], px[1], px[2], px[3]);
        *(uint4*)(dp + 8) = make_uint4(px[4], px[5], px[6], px[7]);
    }
}

// ---------------------------------------------------------------------------
// GEMM core A (m97 structure): C[128 x 128] = A[rows x K] @ B[rows x K]^T,
// K=1024, BK=64. 256 thr = 4 waves (2m x 2n), wave tile 64x64, acc[4][4].
// LDS 32 KB. global_load_lds staging, XOR-swizzled tiles. Source rows are
// taken from per-thread arrays arow/brow (absolute rows) so callers can
// GATHER token rows through the compaction permutation; the swizzle stays
// keyed to the LDS-relative row r (destination layout).
// ---------------------------------------------------------------------------
__device__ __forceinline__ void gemm_core_128128(
    const u16* __restrict__ Ab, const u16* __restrict__ Bb,
    const int (&arow)[4], const int (&brow)[4],
    u16* As, u16* Bs, f32x4 (&acc)[4][4])
{
    const int tid = threadIdx.x, lane = tid & 63;
    const int wm = (tid >> 7) & 1, wn = (tid >> 6) & 1;
    const int frow = lane & 15, quad = lane >> 4;

#pragma unroll
    for (int mi = 0; mi < 4; mi++)
#pragma unroll
        for (int ni = 0; ni < 4; ni++) acc[mi][ni] = (f32x4){0.f, 0.f, 0.f, 0.f};

    for (int k0 = 0; k0 < 1024; k0 += 64) {
#pragma unroll
        for (int i = 0; i < 4; i++) {
            int id = tid + i * 256, r = id >> 3, c = id & 7;
            gll16(Ab + (size_t)arow[i] * 1024 + k0 + (c ^ swz(r)) * 8, As + (size_t)id * 8);
        }
#pragma unroll
        for (int i = 0; i < 4; i++) {
            int id = tid + i * 256, r = id >> 3, c = id & 7;
            gll16(Bb + (size_t)brow[i] * 1024 + k0 + (c ^ swz(r)) * 8, Bs + (size_t)id * 8);
        }
        __syncthreads();
#pragma unroll
        for (int ks = 0; ks < 2; ks++) {
            bf16x8 af[4], bfr[4];
#pragma unroll
            for (int mi = 0; mi < 4; mi++) {
                int r = wm * 64 + mi * 16 + frow;
                af[mi] = lds_frag(As + r * 64 + ((ks * 4 + quad) ^ swz(r)) * 8);
            }
#pragma unroll
            for (int ni = 0; ni < 4; ni++) {
                int r = wn * 64 + ni * 16 + frow;
                bfr[ni] = lds_frag(Bs + r * 64 + ((ks * 4 + quad) ^ swz(r)) * 8);
            }
#pragma unroll
            for (int mi = 0; mi < 4; mi++)
#pragma unroll
                for (int ni = 0; ni < 4; ni++)
                    acc[mi][ni] = __builtin_amdgcn_mfma_f32_16x16x32_bf16(
                        af[mi], bfr[ni], acc[mi][ni], 0, 0, 0);
        }
        __syncthreads();
    }
}

// ---------------------------------------------------------------------------
// GEMM core B (small tile, for oproj where N=1024 would give 1 block/CU
// with the 128x128 tile): C[128 x 64] = A[128xK] @ B[64 x K]^T.
// ---------------------------------------------------------------------------
__device__ __forceinline__ void gemm_core_12864(
    const u16* __restrict__ Ab, const u16* __restrict__ Bb,
    u16* As, u16* Bs, f32x4 (&acc)[4][2])
{
    const int tid = threadIdx.x, lane = tid & 63;
    const int wm = (tid >> 7) & 1, wn = (tid >> 6) & 1;
    const int frow = lane & 15, quad = lane >> 4;

#pragma unroll
    for (int mi = 0; mi < 4; mi++)
#pragma unroll
        for (int ni = 0; ni < 2; ni++) acc[mi][ni] = (f32x4){0.f, 0.f, 0.f, 0.f};

    for (int k0 = 0; k0 < 1024; k0 += 64) {
#pragma unroll
        for (int i = 0; i < 4; i++) {
            int id = tid + i * 256, r = id >> 3, c = id & 7;
            gll16(Ab + (size_t)r * 1024 + k0 + (c ^ swz(r)) * 8, As + (size_t)id * 8);
        }
#pragma unroll
        for (int i = 0; i < 2; i++) {
            int id = tid + i * 256, r = id >> 3, c = id & 7;
            gll16(Bb + (size_t)r * 1024 + k0 + (c ^ swz(r)) * 8, Bs + (size_t)id * 8);
        }
        __syncthreads();
#pragma unroll
        for (int ks = 0; ks < 2; ks++) {
            bf16x8 af[4], bfr[2];
#pragma unroll
            for (int mi = 0; mi < 4; mi++) {
                int r = wm * 64 + mi * 16 + frow;
                af[mi] = lds_frag(As + r * 64 + ((ks * 4 + quad) ^ swz(r)) * 8);
            }
#pragma unroll
            for (int ni = 0; ni < 2; ni++) {
                int r = wn * 32 + ni * 16 + frow;
                bfr[ni] = lds_frag(Bs + r * 64 + ((ks * 4 + quad) ^ swz(r)) * 8);
            }
#pragma unroll
            for (int mi = 0; mi < 4; mi++)
#pragma unroll
                for (int ni = 0; ni < 2; ni++)
                    acc[mi][ni] = __builtin_amdgcn_mfma_f32_16x16x32_bf16(
                        af[mi], bfr[ni], acc[mi][ni], 0, 0, 0);
        }
        __syncthreads();
    }
}

// ---------------------------------------------------------------------------
// Kernel 2: QKV projections, 128x128 tiles, 256 blocks per z.
// COMPACTION-AWARE WORK SKIP (R9-verified: proj dropped out of top-5):
//   z=0: Q (full) -> [B,H,S,DK], PRE-SCALED by C2 = 1/sqrt(DK)*log2e so
//        attn's softmax needs no per-score fmaf (QK^T arrives in log2 units).
//   z=1: K gathers A-rows via invcomp; m-tiles with pos0 >= nkp early-exit.
//   z=2: V gathers B-rows via invcomp -> V'^T; n-tiles >= nkp early-exit.
// Pad rows [nk, nkp) get projections of real masked tokens (finite junk;
// attn's computed bias zeroes their weight). nkp is 128-aligned.
// ---------------------------------------------------------------------------
__global__ __launch_bounds__(256, 3) void mha_proj_qkv(
    const u16* __restrict__ Qb, const u16* __restrict__ Kb, const u16* __restrict__ Vb,
    const u16* __restrict__ Wqt, const u16* __restrict__ Wkt, const u16* __restrict__ Wvt,
    const float* __restrict__ bq, const float* __restrict__ bk, const float* __restrict__ bv,
    const int* __restrict__ invc, const int* __restrict__ nkg,
    u16* __restrict__ Qh, u16* __restrict__ Kh, u16* __restrict__ Vt)
{
    __shared__ __align__(16) u16 As[128 * 64];
    __shared__ __align__(16) u16 Bs[128 * 64];
    const int z = blockIdx.z, bx = blockIdx.x;
    const int tid = threadIdx.x;
    const u16* Ab; const u16* Bb; const float* bias;
    int m0, n0;
    if (z < 2) {
        m0 = (bx & 31) * 128;        // 32 m-tiles minor: XCD = m_t%8, tokens clustered
        n0 = (bx >> 5) * 128;        // 8 n-tiles
        Ab = (z == 0) ? Qb : Kb;
        Bb = (z == 0) ? Wqt : Wkt;
        bias = (z == 0) ? bq : bk;
    } else {
        m0 = (bx >> 5) * 128;        // 8 m-tiles (outdim)
        n0 = (bx & 31) * 128;        // 32 n-tiles minor: XCD = n_t%8, Vb tokens clustered
        Ab = Wvt;
        Bb = Vb;
        bias = bv;
    }

    int arow[4], brow[4];
#pragma unroll
    for (int i = 0; i < 4; i++) {
        int r = (tid + i * 256) >> 3;
        arow[i] = m0 + r;
        brow[i] = n0 + r;
    }
    if (z == 1) {                    // gather K token rows through invcomp
        const int bb = m0 >> 11, pos0 = m0 & 2047;
        const int nkp = (nkg[bb] + 127) & ~127;
        if (pos0 >= nkp) return;     // block-uniform early exit
        const int* ic = invc + ((size_t)bb << 11) + pos0;
#pragma unroll
        for (int i = 0; i < 4; i++) {
            int r = (tid + i * 256) >> 3;
            arow[i] = (bb << 11) + ic[r];
        }
    } else if (z == 2) {             // gather V token rows through invcomp
        const int bj = n0 >> 11, pos0 = n0 & 2047;
        const int nkp = (nkg[bj] + 127) & ~127;
        if (pos0 >= nkp) return;
        const int* ic = invc + ((size_t)bj << 11) + pos0;
#pragma unroll
        for (int i = 0; i < 4; i++) {
            int r = (tid + i * 256) >> 3;
            brow[i] = (bj << 11) + ic[r];
        }
    }

    f32x4 acc[4][4];
    gemm_core_128128(Ab, Bb, arow, brow, As, Bs, acc);

    const int lane = tid & 63;
    const int wm = (tid >> 7) & 1, wn = (tid >> 6) & 1;
    const int frow = lane & 15, quad = lane >> 4;
    u16* dstq = (z == 0) ? Qh : Kh;
    const float qscale = (z == 0) ? 0.18033688f : 1.0f;  // C2 folded into Q
#pragma unroll
    for (int mi = 0; mi < 4; mi++)
#pragma unroll
        for (int ni = 0; ni < 4; ni++)
#pragma unroll
            for (int r = 0; r < 4; r++) {
                int i = m0 + wm * 64 + mi * 16 + quad * 4 + r;
                int j = n0 + wn * 64 + ni * 16 + frow;
                if (z < 2) {
                    float val = (acc[mi][ni][r] + bias[j]) * qscale;
                    int b = i >> 11, s = i & (Sq - 1);   // z=1: s IS compact pos
                    int h = j >> 6, dk = j & (DK - 1);
                    dstq[((size_t)(b * Hn + h) * Sq + s) * DK + dk] = f2bf(val);
                } else {
                    float val = acc[mi][ni][r] + bias[i];
                    int h = i >> 6, dk = i & (DK - 1);
                    int bj = j >> 11, cs = j & (Sq - 1); // compact pos
                    int sp = (cs & ~12) | ((cs & 4) << 1) | ((cs & 8) >> 1);  // swap bits 2,3
                    Vt[((size_t)(bj * Hn + h) * DK + dk) * Sq + sp] = f2bf(val);
                }
            }
}

// ---------------------------------------------------------------------------
// Kernel 3: flash attention over COMPACTED keys. Inner math = frozen R4
// body (R9-verified: VGPR 52, WRITE_SIZE 8192 KB no-spill, 44.0 us,
// VALUBusy ~50% -> VALU-limited softmax). R10 changes (VALU diet only):
//  (a) Q pre-scaled by C2 in proj -> softmax exp2 takes sT directly (no
//      fmaf per score).
//  (b) full-tile fast path: (it+1)*128 <= nk is BLOCK-UNIFORM -> full
//      tiles skip the per-element bias select entirely; only the single
//      boundary tile pays cmp+cndmask.
// Staging/combine/launch config untouched: double-buffered counted-vmcnt
// staging (stage t+1, s_waitcnt vmcnt(4), sched_barrier(0), raw s_barrier).
// SPILL GUARD: WRITE_SIZE must stay 8192 KB. __launch_bounds__(512,4);
// DO NOT raise the min-waves arg ((512,8) spilled catastrophically, R3).
// ---------------------------------------------------------------------------
__global__ __launch_bounds__(512, 4) void mha_attn(
    const u16* __restrict__ Qh, const u16* __restrict__ Kh, const u16* __restrict__ Vt,
    const int* __restrict__ nkg, u16* __restrict__ X)
{
    const int bh = blockIdx.x;                 // b*16+h -> XCD = bh%8
    const int b = bh >> 4;
    const int q0 = blockIdx.y * 64;
    const int tid = threadIdx.x, lane = tid & 63, w = tid >> 6;
    const int wq = w & 1, p = w >> 1;          // q-group, key-parity 0..3
    const int qc = lane & 31, half = lane >> 5;

    // 2 buffers x (K tile 16 KB | V tile 16 KB); aliased as 32 KB combine
    // scratch after the k-loop. Per-buffer layout: [Ks 8192 u16][Vs 8192 u16].
    __shared__ __align__(16) u16 SB[2 * 16384];
    __shared__ float lsl[256];

    const u16* Qp = Qh + (size_t)bh * Sq * DK;
    const u16* Kp = Kh + (size_t)bh * Sq * DK;
    const u16* Vp = Vt + (size_t)bh * DK * Sq;
    const int nk = nkg[b];
    const int nt = (nk + 127) >> 7;            // tiles of 128 compacted keys

    // Q B-frags direct from global (once): lane n=qc; k = kc*16 + half*8 + j
    bf16x8 qf[4];
    {
        const u16* qrow = Qp + (size_t)(q0 + wq * 32 + qc) * DK + half * 8;
#pragma unroll
        for (int kc = 0; kc < 4; kc++) qf[kc] = gfrag(qrow + kc * 16);
    }

    // staging precompute: 4 gll16 per tile (2 K + 2 V), 32 KB/tile
    const int idA = tid, idB = tid + 512;
    const u16* ksA = Kp + (size_t)(idA >> 3) * DK + ((idA & 7) ^ swz(idA >> 3)) * 8;
    const u16* ksB = Kp + (size_t)(idB >> 3) * DK + ((idB & 7) ^ swz(idB >> 3)) * 8;
    const u16* vsA = Vp + (size_t)(idA >> 4) * Sq + (((idA & 15) ^ ((idA >> 4) & 15)) * 8);
    const u16* vsB = Vp + (size_t)(idB >> 4) * Sq + (((idB & 15) ^ ((idB >> 4) & 15)) * 8);
    u16* kdA = SB + idA * 8;
    u16* kdB = SB + idB * 8;
    u16* vdA = SB + 8192 + idA * 8;
    u16* vdB = SB + 8192 + idB * 8;

    auto stage = [&](int cur, int kb) {
        const int co = cur * 16384;
        gll16(ksA + (size_t)kb * DK, kdA + co);
        gll16(ksB + (size_t)kb * DK, kdB + co);
        gll16(vsA + kb, vdA + co);
        gll16(vsB + kb, vdB + co);
    };

    // fragment LDS offsets (loop-invariant, relative to buffer base)
    const int kr = p * 32 + qc;
    int kfo[4];
#pragma unroll
    for (int kc = 0; kc < 4; kc++)
        kfo[kc] = kr * 64 + (((kc * 2 + half) ^ swz(kr)) * 8);
    int vfo0[2], vfo1[2];
#pragma unroll
    for (int kc = 0; kc < 2; kc++) {
        int ch = p * 4 + kc * 2 + half;
        vfo0[kc] = qc * 128 + ((ch ^ (qc & 15)) * 8);
        vfo1[kc] = (32 + qc) * 128 + ((ch ^ (qc & 15)) * 8);
    }
    const int kbias = p * 32 + 4 * half;       // + kb + 8g + r = key index

    float l_l = 0.f;
    f32x16 o0, o1;
#pragma unroll
    for (int i = 0; i < 16; i++) { o0[i] = 0.f; o1[i] = 0.f; }

    stage(0, 0);
    for (int it = 0; it < nt; it++) {
        const int cur = it & 1;
        if (it + 1 < nt) {
            stage(cur ^ 1, (it + 1) * 128);
            asm volatile("s_waitcnt vmcnt(4)" ::: "memory");  // tile t done, t+1 in flight
        } else {
            asm volatile("s_waitcnt vmcnt(0)" ::: "memory");
        }
        __builtin_amdgcn_sched_barrier(0);
        __builtin_amdgcn_s_barrier();

        const u16* Kl = SB + cur * 16384;
        const u16* Vl = Kl + 8192;

        // ---- S^T = K Q^T on this wave's 32-key slice (log2 units) ----
        f32x16 sT;
#pragma unroll
        for (int i = 0; i < 16; i++) sT[i] = 0.f;
        __builtin_amdgcn_s_setprio(1);
#pragma unroll
        for (int kc = 0; kc < 4; kc++) {
            bf16x8 ka = lds_frag(Kl + kfo[kc]);
            sT = __builtin_amdgcn_mfma_f32_32x32x16_bf16(ka, qf[kc], sT, 0, 0, 0);
        }
        __builtin_amdgcn_s_setprio(0);

        // ---- softmax: Q pre-scaled -> pure exp2. Full tiles (block-
        // uniform predicate) skip the bias select entirely. ----
        float t[16], rs = 0.f;
        if ((it + 1) * 128 <= nk) {            // full tile: all keys active
#pragma unroll
            for (int i = 0; i < 16; i++) {
                float a = __builtin_amdgcn_exp2f(sT[i]);
                t[i] = a; rs += a;
            }
        } else {                               // boundary tile (at most one)
            const int thr = nk - it * 128 - kbias; // key<nk <=> 8g+r < thr
#pragma unroll
            for (int g = 0; g < 4; g++)
#pragma unroll
                for (int r = 0; r < 4; r++) {
                    float a = (8 * g + r < thr)
                        ? __builtin_amdgcn_exp2f(sT[g * 4 + r]) : 0.f;
                    t[g * 4 + r] = a; rs += a;
                }
        }
        l_l += rs;

        // ---- pack P (register-resident; slot = key w/ bits2,3 swapped) ----
        u32 pk[8];
#pragma unroll
        for (int i = 0; i < 8; i++) pk[i] = pack_bf16(t[2 * i], t[2 * i + 1]);

        // ---- O^T += V P^T (2 MFMAs of k=16 per d-half) ----
        __builtin_amdgcn_s_setprio(1);
#pragma unroll
        for (int kc = 0; kc < 2; kc++) {
            bf16x8 pf = __builtin_bit_cast(bf16x8,
                make_uint4(pk[4 * kc], pk[4 * kc + 1], pk[4 * kc + 2], pk[4 * kc + 3]));
            bf16x8 va0 = lds_frag(Vl + vfo0[kc]);
            bf16x8 va1 = lds_frag(Vl + vfo1[kc]);
            o0 = __builtin_amdgcn_mfma_f32_32x32x16_bf16(va0, pf, o0, 0, 0, 0);
            o1 = __builtin_amdgcn_mfma_f32_32x32x16_bf16(va1, pf, o1, 0, 0, 0);
        }
        __builtin_amdgcn_s_setprio(0);
        __builtin_amdgcn_s_barrier();          // release buffer cur for re-stage
    }

    // ---- tree combine of 4 key-parity partials (2 barriers) ----
    l_l += __shfl_xor(l_l, 32);
    float* fcb = (float*)SB;                 // 32 KB = 4 segs x 8 KB
    if (p >= 2) {                            // round 1 write: p=2->seg(wq,0), p=3->seg(wq,1)
        float* fc = fcb + (size_t)(wq * 2 + (p & 1)) * 2048;
#pragma unroll
        for (int r = 0; r < 16; r++) fc[r * 64 + lane] = o0[r];
#pragma unroll
        for (int r = 0; r < 16; r++) fc[(16 + r) * 64 + lane] = o1[r];
        lsl[(wq * 2 + (p & 1)) * 64 + lane] = l_l;
    }
    __syncthreads();
    if (p < 2) {                             // round 1 add (parallel on p=0,1)
        float* fc = fcb + (size_t)(wq * 2 + p) * 2048;
#pragma unroll
        for (int r = 0; r < 16; r++) o0[r] += fc[r * 64 + lane];
#pragma unroll
        for (int r = 0; r < 16; r++) o1[r] += fc[(16 + r) * 64 + lane];
        l_l += lsl[(wq * 2 + p) * 64 + lane];
    }
    if (p == 1) {                            // round 2 write (same seg it just read)
        float* fc = fcb + (size_t)(wq * 2 + 1) * 2048;
#pragma unroll
        for (int r = 0; r < 16; r++) fc[r * 64 + lane] = o0[r];
#pragma unroll
        for (int r = 0; r < 16; r++) fc[(16 + r) * 64 + lane] = o1[r];
        lsl[(wq * 2 + 1) * 64 + lane] = l_l;
    }
    __syncthreads();
    if (p == 0) {
        float* fc = fcb + (size_t)(wq * 2 + 1) * 2048;
#pragma unroll
        for (int r = 0; r < 16; r++) o0[r] += fc[r * 64 + lane];
#pragma unroll
        for (int r = 0; r < 16; r++) o1[r] += fc[(16 + r) * 64 + lane];
        l_l += lsl[(wq * 2 + 1) * 64 + lane];
        float inv = 1.0f / l_l;
        const int qg = q0 + wq * 32 + qc;
        u16* Xp = X + (size_t)(b * Sq + qg) * Dm + (bh & 15) * DK;
#pragma unroll
        for (int g = 0; g < 4; g++) {
            *(uint2*)&Xp[8 * g + 4 * half] =
                make_uint2(pack_bf16(o0[g * 4 + 0] * inv, o0[g * 4 + 1] * inv),
                           pack_bf16(o0[g * 4 + 2] * inv, o0[g * 4 + 3] * inv));
            *(uint2*)&Xp[32 + 8 * g + 4 * half] =
                make_uint2(pack_bf16(o1[g * 4 + 0] * inv, o1[g * 4 + 1] * inv),
                           pack_bf16(o1[g * 4 + 2] * inv, o1[g * 4 + 3] * inv));
        }
    }
}

// ---------------------------------------------------------------------------
// Kernel 4: out = X @ Wo + bo (fp32). 128x64 tiles, m-major -> 512 blocks
// (2 blocks/CU; the 128x128 tile would leave 1/CU here).
// ---------------------------------------------------------------------------
__global__ __launch_bounds__(256) void mha_oproj(
    const u16* __restrict__ X, const u16* __restrict__ Wot,
    const float* __restrict__ bo, float* __restrict__ out)
{
    __shared__ __align__(16) u16 As[128 * 64];
    __shared__ __align__(16) u16 Bs[64 * 64];
    const int bx = blockIdx.x;
    const int m0 = (bx & 31) * 128, n0 = (bx >> 5) * 64;
    f32x4 acc[4][2];
    gemm_core_12864(X + (size_t)m0 * Dm, Wot + (size_t)n0 * Dm, As, Bs, acc);
    const int tid = threadIdx.x, lane = tid & 63;
    const int wm = (tid >> 7) & 1, wn = (tid >> 6) & 1;
    const int frow = lane & 15, quad = lane >> 4;
#pragma unroll
    for (int mi = 0; mi < 4; mi++)
#pragma unroll
        for (int ni = 0; ni < 2; ni++)
#pragma unroll
            for (int r = 0; r < 4; r++) {
                int m = m0 + wm * 64 + mi * 16 + quad * 4 + r;
                int n = n0 + wn * 32 + ni * 16 + frow;
                out[(size_t)m * Dm + n] = acc[mi][ni][r] + bo[n];
            }
}

// ---------------------------------------------------------------------------
extern "C" void kernel_launch(void* const* d_in, const int* in_sizes, int n_in,
                              void* d_out, int out_size, void* d_ws, size_t ws_size,
                              hipStream_t stream)
{
    const float* qin  = (const float*)d_in[0];
    const float* kin  = (const float*)d_in[1];
    const float* vin  = (const float*)d_in[2];
    const int*   mask = (const int*)d_in[3];
    const float* Wq   = (const float*)d_in[4];
    const float* bq   = (const float*)d_in[5];
    const float* Wk   = (const float*)d_in[6];
    const float* bk   = (const float*)d_in[7];
    const float* Wv   = (const float*)d_in[8];
    const float* bv   = (const float*)d_in[9];
    const float* Wo   = (const float*)d_in[10];
    const float* bo   = (const float*)d_in[11];
    float* out = (float*)d_out;

    u16* ws = (u16*)d_ws;
    const size_t MW = (size_t)Dm * Dm;
    const size_t MT = (size_t)Bz * Sq * Dm;
    u16* Wqt = ws;
    u16* Wkt = ws + MW;
    u16* Wvt = ws + 2 * MW;
    u16* Wot = ws + 3 * MW;
    u16* Qb  = ws + 4 * MW;
    u16* Kb  = Qb + MT;
    u16* Vb  = Kb + MT;
    u16* Qh  = Vb + MT;
    u16* Kh  = Qh + MT;
    u16* Vt  = Kh + MT;
    int*   invcg = (int*)(Vt + MT);            // 16 KB (compact pos -> token)
    int*   nkg   = invcg + Bz * Sq;            // 2 ints (#active keys per b)
    u16* X   = Qb;                             // Qb dead after proj

    hipLaunchKernelGGL(mha_prep, dim3(2048, 1, 4), dim3(256), 0, stream,
                       qin, kin, vin, Wq, Wk, Wv, Wo, mask, Qb, Wqt, invcg, nkg);
    hipLaunchKernelGGL(mha_proj_qkv, dim3(256, 1, 3), dim3(256), 0, stream,
                       Qb, Kb, Vb, Wqt, Wkt, Wvt, bq, bk, bv, invcg, nkg, Qh, Kh, Vt);
    hipLaunchKernelGGL(mha_attn, dim3(32, 32), dim3(512), 0, stream,
                       Qh, Kh, Vt, nkg, X);
    hipLaunchKernelGGL(mha_oproj, dim3(512), dim3(256), 0, stream,
                       X, Wot, bo, out);
}